// Round 2
// baseline (1897.625 us; speedup 1.0000x reference)
//
#include <hip/hip_runtime.h>
#include <stdint.h>
#include <math.h>

// ---------------------------------------------------------------------------
// HybridTransformerBlock: LN1 -> v=h@W_in+b -> per-head MPS scan -> +x
//                         LN2 -> GELU FFN -> +x2
// B=4 S=2048 D=1024 H=16 DH=32 DP=64 DFF=4096
// Workspace-adaptive: Mt (scan transfer matrices) and f1 (FFN mid) are
// chunked to fit whatever ws_size the harness provides.
// ---------------------------------------------------------------------------

typedef __attribute__((ext_vector_type(8))) __bf16 bf16x8;   // MFMA A/B operand
typedef __attribute__((ext_vector_type(8))) short  s16x8;    // raw 16B load
typedef __attribute__((ext_vector_type(4))) float  f32x4;    // MFMA C/D

__device__ __forceinline__ float bf2f(unsigned short u) {
  union { unsigned int i; float f; } c; c.i = ((unsigned int)u) << 16; return c.f;
}
__device__ __forceinline__ unsigned short f2bf(float f) {
  union { float f; unsigned int i; } c; c.f = f;
  unsigned int x = c.i;
  return (unsigned short)((x + 0x7FFFu + ((x >> 16) & 1u)) >> 16);
}

// ---------------------------------------------------------------------------
// LayerNorm (fp32 in) -> bf16 out.  One block per row of 1024.
// ---------------------------------------------------------------------------
__global__ __launch_bounds__(256)
void ln_bf16_kernel(const float* __restrict__ x, const float* __restrict__ g,
                    const float* __restrict__ b, unsigned short* __restrict__ out)
{
  const int row = blockIdx.x;
  const int t = threadIdx.x;
  const float4 v = ((const float4*)(x + (size_t)row * 1024))[t];
  float s  = v.x + v.y + v.z + v.w;
  float s2 = v.x*v.x + v.y*v.y + v.z*v.z + v.w*v.w;
#pragma unroll
  for (int o = 32; o > 0; o >>= 1) { s += __shfl_down(s, o, 64); s2 += __shfl_down(s2, o, 64); }
  __shared__ float ws1[4], ws2[4];
  if ((t & 63) == 0) { ws1[t >> 6] = s; ws2[t >> 6] = s2; }
  __syncthreads();
  const float ts  = ws1[0] + ws1[1] + ws1[2] + ws1[3];
  const float ts2 = ws2[0] + ws2[1] + ws2[2] + ws2[3];
  const float mean = ts * (1.0f / 1024.0f);
  const float var  = ts2 * (1.0f / 1024.0f) - mean * mean;
  const float inv  = rsqrtf(var + 1e-5f);
  const float4 gg = ((const float4*)g)[t];
  const float4 bb = ((const float4*)b)[t];
  ushort4 o4;
  o4.x = f2bf((v.x - mean) * inv * gg.x + bb.x);
  o4.y = f2bf((v.y - mean) * inv * gg.y + bb.y);
  o4.z = f2bf((v.z - mean) * inv * gg.z + bb.z);
  o4.w = f2bf((v.w - mean) * inv * gg.w + bb.w);
  ((ushort4*)(out + (size_t)row * 1024))[t] = o4;
}

// ---------------------------------------------------------------------------
// Generic fp32 [R,C] -> bf16 [C,R] transpose-convert (weights, tiny)
// ---------------------------------------------------------------------------
__global__ __launch_bounds__(256)
void transpose_to_bf16(const float* __restrict__ src, unsigned short* __restrict__ dst,
                       int R, int C)
{
  const int idx = blockIdx.x * 256 + threadIdx.x;
  const int c = idx / R;
  const int r = idx - c * R;
  dst[idx] = f2bf(src[(size_t)r * C + c]);
}

// A[h,i,p,j] -> A3[h][(i*32+j)][p]  (bf16), total 16*1024*64 = 1M elements
__global__ __launch_bounds__(256)
void build_a3(const float* __restrict__ A, unsigned short* __restrict__ dst)
{
  const int idx = blockIdx.x * 256 + threadIdx.x;
  const int h = idx >> 16;
  const int rem = idx & 65535;
  const int n = rem >> 6;        // i*32 + j
  const int p = rem & 63;
  const int i = n >> 5, j = n & 31;
  dst[idx] = f2bf(A[(((size_t)h * 32 + i) * 64 + p) * 32 + j]);
}

// ---------------------------------------------------------------------------
// bf16 MFMA GEMM, C = A[M,K] * B  with B supplied transposed: BT[N,K].
// 128x128 tile, BK=32, 256 threads (4 waves, each 64x64), global_load_lds.
// EPI: 0 = bf16 out (+bias)                      (v = h@W_in+b_in)
//      1 = bf16 out to Mt chunk, (i,j)->(j,i) swizzled, blockIdx.z=head.
//          Local row' = b*SC + sc maps to global v row b*2048 + s0 + sc.
//      2 = f32 out = resid + acc + bias          (residual adds)
//      3 = bf16 out = gelu_exact(acc+bias)       (FFN mid)
// ---------------------------------------------------------------------------
#define BM 128
#define BN 128
#define BKK 32

template<int EPI>
__global__ __launch_bounds__(256)
void gemm_bt(const unsigned short* __restrict__ Abase, int lda,
             const unsigned short* __restrict__ BTbase, int ldb,
             const float* __restrict__ bias,
             const float* __restrict__ resid,
             void* __restrict__ Cout,
             int N, int K, int s0, int lsc)
{
  __shared__ __align__(16) unsigned short As[BM * BKK];
  __shared__ __align__(16) unsigned short Bs[BN * BKK];
  const int tid  = threadIdx.x;
  const int lane = tid & 63;
  const int m0 = blockIdx.x * BM;
  const int n0 = blockIdx.y * BN;
  const unsigned short* Ap  = Abase;
  const unsigned short* BTp = BTbase;
  if (EPI == 1) {
    const int h = blockIdx.z;
    Ap  += h * 64;                       // head column slice of v (lda=1024)
    BTp += (size_t)h * 1024 * 64;        // A3 per-head block
  }
  f32x4 acc[4][4] = {};
  const int wave = tid >> 6;
  const int wr = wave >> 1, wc = wave & 1;
  const int mrow = lane & 15;
  const int koff = (lane >> 4) * 8;
  const int SCm1 = (1 << lsc) - 1;

  for (int kk = 0; kk < K; kk += BKK) {
    // ---- stage A, B tiles (16B per lane per load) ----
#pragma unroll
    for (int rep = 0; rep < 2; ++rep) {
      const int c = rep * 256 + tid;                  // chunk id 0..511
      const int rowp = m0 + (c >> 2);
      size_t grow;
      if (EPI == 1) grow = ((size_t)(rowp >> lsc) << 11) + (size_t)s0 + (rowp & SCm1);
      else          grow = (size_t)rowp;
      const unsigned short* ga = Ap + grow * lda + kk + (c & 3) * 8;
      unsigned short* la = &As[(size_t)(rep * 256 + (tid & 192)) * 8];
      __builtin_amdgcn_global_load_lds(
          (const __attribute__((address_space(1))) unsigned int*)ga,
          (__attribute__((address_space(3))) unsigned int*)la, 16, 0, 0);
      const unsigned short* gb = BTp + (size_t)(n0 + (c >> 2)) * ldb + kk + (c & 3) * 8;
      unsigned short* lb = &Bs[(size_t)(rep * 256 + (tid & 192)) * 8];
      __builtin_amdgcn_global_load_lds(
          (const __attribute__((address_space(1))) unsigned int*)gb,
          (__attribute__((address_space(3))) unsigned int*)lb, 16, 0, 0);
    }
    __syncthreads();                                   // vmcnt drain + barrier
    bf16x8 af[4], bfr[4];
#pragma unroll
    for (int a = 0; a < 4; ++a)
      af[a] = *(const bf16x8*)&As[(wr * 64 + a * 16 + mrow) * BKK + koff];
#pragma unroll
    for (int b = 0; b < 4; ++b)
      bfr[b] = *(const bf16x8*)&Bs[(wc * 64 + b * 16 + mrow) * BKK + koff];
#pragma unroll
    for (int a = 0; a < 4; ++a)
#pragma unroll
      for (int b = 0; b < 4; ++b)
        acc[a][b] = __builtin_amdgcn_mfma_f32_16x16x32_bf16(af[a], bfr[b], acc[a][b], 0, 0, 0);
    __syncthreads();                                   // protect LDS for next stage
  }

  // ---- epilogue ----
  const int crow = m0 + wr * 64 + (lane >> 4) * 4;
  const int ccol = n0 + wc * 64 + (lane & 15);
#pragma unroll
  for (int a = 0; a < 4; ++a) {
#pragma unroll
    for (int b = 0; b < 4; ++b) {
      const int col = ccol + b * 16;
#pragma unroll
      for (int q = 0; q < 4; ++q) {
        const int row = crow + a * 16 + q;
        const float val = acc[a][b][q];
        if (EPI == 0) {
          ((unsigned short*)Cout)[(size_t)row * N + col] = f2bf(val + bias[col]);
        } else if (EPI == 1) {
          const int bb = row >> lsc, sc = row & SCm1;  // local chunk coords
          const int h = blockIdx.z;
          const size_t off = ((((size_t)(bb * 16 + h)) << lsc) + sc) * 1024
                           + (size_t)(col & 31) * 32 + (col >> 5);   // [j][i]
          ((unsigned short*)Cout)[off] = f2bf(val);
        } else if (EPI == 2) {
          const size_t o = (size_t)row * N + col;
          ((float*)Cout)[o] = resid[o] + val + bias[col];
        } else {
          const float xv = val + bias[col];
          const float gl = 0.5f * xv * (1.0f + erff(xv * 0.70710678118654752f));
          ((unsigned short*)Cout)[(size_t)row * N + col] = f2bf(gl);
        }
      }
    }
  }
}

// ---------------------------------------------------------------------------
// MPS recurrence over one S-chunk.  One wave per (b,h); lane j (both halves)
// holds h[j].  Mt[bh][sc][j][i] (bf16): lane reads its contiguous 16 i's
// (32B), half sums i in [16*half,16*half+16), cross-half shfl_xor combines.
// Bond vector carried across chunk launches in hstate (fp32[64][32]).
// ---------------------------------------------------------------------------
__global__ __launch_bounds__(64)
void mps_scan_chunk(const unsigned short* __restrict__ Mt,
                    unsigned short* __restrict__ hs,
                    float* __restrict__ hstate, int s0, int SC)
{
  const int bh = blockIdx.x;           // b*16 + h
  const int b = bh >> 4, h = bh & 15;
  const int lane = threadIdx.x;
  const int j = lane & 31, half = lane >> 5;
  const unsigned short* base = Mt + (size_t)bh * SC * 1024 + j * 32 + half * 16;
  unsigned short* hout = hs + ((size_t)b * 2048 + s0) * 512 + h * 32 + j;
  float hc = (s0 == 0) ? 0.17677669529663687f : hstate[bh * 32 + j];
  s16x8 c0 = *(const s16x8*)(base);
  s16x8 c1 = *(const s16x8*)(base + 8);
  for (int s = 0; s < SC; ++s) {
    s16x8 n0 = c0, n1 = c1;
    if (s + 1 < SC) {                  // prefetch next step's M column slice
      const unsigned short* nb = base + (size_t)(s + 1) * 1024;
      n0 = *(const s16x8*)(nb);
      n1 = *(const s16x8*)(nb + 8);
    }
    float a0 = 0.f, a1 = 0.f;
#pragma unroll
    for (int ii = 0; ii < 8; ++ii) {
      const float hm = __shfl(hc, half * 16 + ii, 64);
      a0 = fmaf(hm, bf2f((unsigned short)c0[ii]), a0);
    }
#pragma unroll
    for (int ii = 0; ii < 8; ++ii) {
      const float hm = __shfl(hc, half * 16 + 8 + ii, 64);
      a1 = fmaf(hm, bf2f((unsigned short)c1[ii]), a1);
    }
    float tot = a0 + a1;
    tot += __shfl_xor(tot, 32, 64);
    const float e = __expf(2.0f * tot);
    hc = 1.0f - 2.0f / (e + 1.0f);     // tanh, saturates correctly at +-inf
    if (half == 0) hout[(size_t)s * 512] = f2bf(hc);
    c0 = n0; c1 = n1;
  }
  if (half == 0) hstate[bh * 32 + j] = hc;
}

// ---------------------------------------------------------------------------
extern "C" void kernel_launch(void* const* d_in, const int* in_sizes, int n_in,
                              void* d_out, int out_size, void* d_ws, size_t ws_size,
                              hipStream_t stream)
{
  const float* x     = (const float*)d_in[0];
  const float* ln1g  = (const float*)d_in[1];
  const float* ln1b  = (const float*)d_in[2];
  const float* W_in  = (const float*)d_in[3];
  const float* b_in  = (const float*)d_in[4];
  const float* Amps  = (const float*)d_in[5];
  const float* W_out = (const float*)d_in[6];
  const float* b_out = (const float*)d_in[7];
  const float* ln2g  = (const float*)d_in[8];
  const float* ln2b  = (const float*)d_in[9];
  const float* W1    = (const float*)d_in[10];
  const float* b1    = (const float*)d_in[11];
  const float* W2    = (const float*)d_in[12];
  const float* b2    = (const float*)d_in[13];
  float* out = (float*)d_out;          // also serves as x2 (branch-1 residual)

  char* w = (char*)d_ws;
  size_t off = 0;
  auto alloc = [&](size_t bytes) {
    char* p = w + off; off += (bytes + 255) & ~(size_t)255; return p;
  };
  unsigned short* W_inT  = (unsigned short*)alloc(2ull * 1024 * 1024);
  unsigned short* W_outT = (unsigned short*)alloc(2ull * 1024 * 512);
  unsigned short* W1T    = (unsigned short*)alloc(2ull * 4096 * 1024);
  unsigned short* W2T    = (unsigned short*)alloc(2ull * 1024 * 4096);
  unsigned short* A3     = (unsigned short*)alloc(2ull * 16 * 1024 * 64);
  unsigned short* hb     = (unsigned short*)alloc(2ull * 8192 * 1024);
  unsigned short* vb     = (unsigned short*)alloc(2ull * 8192 * 1024);
  float*          hstate = (float*)alloc(4ull * 64 * 32);
  const size_t fixed = off;

  // --- choose Mt S-chunk (SC) and FFN row-chunk (MC) to fit ws_size ---
  auto mt_bytes = [](int sc) { return (size_t)64 * sc * 1024 * 2; };
  auto f1_bytes = [](int mc) { return (size_t)mc * 4096 * 2; };
  const size_t avail = (ws_size > fixed + 256) ? (ws_size - fixed - 256) : 0;
  int SC = 2048, MC = 8192;
  for (;;) {
    const size_t ma = mt_bytes(SC), fa = f1_bytes(MC);
    const size_t region = ma > fa ? ma : fa;
    if (region <= avail) break;
    if (ma >= fa && SC > 128) SC >>= 1;
    else if (MC > 1024)       MC >>= 1;
    else if (SC > 128)        SC >>= 1;
    else break;                          // minimal config; proceed regardless
  }
  int lsc = 0; while ((1 << lsc) < SC) ++lsc;
  const size_t ma = mt_bytes(SC), fa = f1_bytes(MC);
  unsigned short* Mt = (unsigned short*)alloc(ma > fa ? ma : fa);
  unsigned short* f1 = Mt;              // temporally disjoint with Mt use
  unsigned short* hsb = hb;             // h dead after v-GEMM; hs dead before LN2
  unsigned short* h2b = hb;             // LN2 output overwrites hs (then dead)

  // weight prep (runs every call; tiny)
  transpose_to_bf16<<<4096,  256, 0, stream>>>(W_in,  W_inT,  1024, 1024);
  transpose_to_bf16<<<2048,  256, 0, stream>>>(W_out, W_outT, 512,  1024);
  transpose_to_bf16<<<16384, 256, 0, stream>>>(W1,    W1T,    1024, 4096);
  transpose_to_bf16<<<16384, 256, 0, stream>>>(W2,    W2T,    4096, 1024);
  build_a3<<<4096, 256, 0, stream>>>(Amps, A3);

  // branch 1: MPS recurrence
  ln_bf16_kernel<<<8192, 256, 0, stream>>>(x, ln1g, ln1b, hb);
  gemm_bt<0><<<dim3(64, 8, 1), 256, 0, stream>>>(hb, 1024, W_inT, 1024, b_in, nullptr, vb, 1024, 1024, 0, 0);
  for (int s0 = 0; s0 < 2048; s0 += SC) {
    gemm_bt<1><<<dim3(4 * SC / 128, 8, 16), 256, 0, stream>>>(vb, 1024, A3, 64, nullptr, nullptr, Mt, 1024, 64, s0, lsc);
    mps_scan_chunk<<<64, 64, 0, stream>>>(Mt, hsb, hstate, s0, SC);
  }
  gemm_bt<2><<<dim3(64, 8, 1), 256, 0, stream>>>(hsb, 512, W_outT, 512, b_out, x, out, 1024, 512, 0, 0);

  // branch 2: FFN (out holds x2; final GEMM adds residual in place)
  ln_bf16_kernel<<<8192, 256, 0, stream>>>(out, ln2g, ln2b, h2b);
  for (int r0 = 0; r0 < 8192; r0 += MC) {
    gemm_bt<3><<<dim3(MC / 128, 32, 1), 256, 0, stream>>>(h2b + (size_t)r0 * 1024, 1024, W1T, 1024, b1, nullptr, f1, 4096, 1024, 0, 0);
    gemm_bt<2><<<dim3(MC / 128, 8, 1), 256, 0, stream>>>(f1, 4096, W2T, 4096, b2, out + (size_t)r0 * 1024, out + (size_t)r0 * 1024, 1024, 4096, 0, 0);
  }

  (void)in_sizes; (void)n_in; (void)out_size; (void)ws_size;
}

// Round 3
// 1841.600 us; speedup vs baseline: 1.0304x; 1.0304x over previous
//
#include <hip/hip_runtime.h>
#include <stdint.h>
#include <math.h>

// ---------------------------------------------------------------------------
// HybridTransformerBlock: LN1 -> v=h@W_in+b -> per-head MPS scan -> +x
//                         LN2 -> GELU FFN -> +x2
// B=4 S=2048 D=1024 H=16 DH=32 DP=64 DFF=4096
// Workspace-adaptive: Mt (scan transfer matrices) and f1 (FFN mid) are
// chunked to fit whatever ws_size the harness provides.
// ---------------------------------------------------------------------------

typedef __attribute__((ext_vector_type(8))) __bf16 bf16x8;   // MFMA A/B operand
typedef __attribute__((ext_vector_type(8))) short  s16x8;    // raw 16B load
typedef __attribute__((ext_vector_type(4))) float  f32x4;    // MFMA C/D

__device__ __forceinline__ float bf2f(unsigned short u) {
  union { unsigned int i; float f; } c; c.i = ((unsigned int)u) << 16; return c.f;
}
__device__ __forceinline__ unsigned short f2bf(float f) {
  union { float f; unsigned int i; } c; c.f = f;
  unsigned int x = c.i;
  return (unsigned short)((x + 0x7FFFu + ((x >> 16) & 1u)) >> 16);
}

// ---------------------------------------------------------------------------
// LayerNorm (fp32 in) -> bf16 out.  One block per row of 1024.
// ---------------------------------------------------------------------------
__global__ __launch_bounds__(256)
void ln_bf16_kernel(const float* __restrict__ x, const float* __restrict__ g,
                    const float* __restrict__ b, unsigned short* __restrict__ out)
{
  const int row = blockIdx.x;
  const int t = threadIdx.x;
  const float4 v = ((const float4*)(x + (size_t)row * 1024))[t];
  float s  = v.x + v.y + v.z + v.w;
  float s2 = v.x*v.x + v.y*v.y + v.z*v.z + v.w*v.w;
#pragma unroll
  for (int o = 32; o > 0; o >>= 1) { s += __shfl_down(s, o, 64); s2 += __shfl_down(s2, o, 64); }
  __shared__ float ws1[4], ws2[4];
  if ((t & 63) == 0) { ws1[t >> 6] = s; ws2[t >> 6] = s2; }
  __syncthreads();
  const float ts  = ws1[0] + ws1[1] + ws1[2] + ws1[3];
  const float ts2 = ws2[0] + ws2[1] + ws2[2] + ws2[3];
  const float mean = ts * (1.0f / 1024.0f);
  const float var  = ts2 * (1.0f / 1024.0f) - mean * mean;
  const float inv  = rsqrtf(var + 1e-5f);
  const float4 gg = ((const float4*)g)[t];
  const float4 bb = ((const float4*)b)[t];
  ushort4 o4;
  o4.x = f2bf((v.x - mean) * inv * gg.x + bb.x);
  o4.y = f2bf((v.y - mean) * inv * gg.y + bb.y);
  o4.z = f2bf((v.z - mean) * inv * gg.z + bb.z);
  o4.w = f2bf((v.w - mean) * inv * gg.w + bb.w);
  ((ushort4*)(out + (size_t)row * 1024))[t] = o4;
}

// ---------------------------------------------------------------------------
// Coalesced LDS-tiled fp32 [R,C] -> bf16 [C,R] transpose.  32x32 tiles.
// Grid (C/32, R/32), block 256.
// ---------------------------------------------------------------------------
__global__ __launch_bounds__(256)
void transpose_tile_bf16(const float* __restrict__ src, unsigned short* __restrict__ dst,
                         int R, int C)
{
  __shared__ float ls[32 * 33];
  const int t = threadIdx.x;
  const int c0 = blockIdx.x * 32, r0 = blockIdx.y * 32;
  const int tr = t >> 3, tc = (t & 7) * 4;
  const float4 v = *(const float4*)(src + (size_t)(r0 + tr) * C + c0 + tc);
  ls[tr * 33 + tc + 0] = v.x;
  ls[tr * 33 + tc + 1] = v.y;
  ls[tr * 33 + tc + 2] = v.z;
  ls[tr * 33 + tc + 3] = v.w;
  __syncthreads();
  const int oc = t >> 3;           // source col handled by this thread
  const int orr = (t & 7) * 4;     // source row group
  ushort4 o;
  o.x = f2bf(ls[(orr + 0) * 33 + oc]);
  o.y = f2bf(ls[(orr + 1) * 33 + oc]);
  o.z = f2bf(ls[(orr + 2) * 33 + oc]);
  o.w = f2bf(ls[(orr + 3) * 33 + oc]);
  *(ushort4*)(dst + (size_t)(c0 + oc) * R + r0 + orr) = o;
}

// ---------------------------------------------------------------------------
// A[h,i,p,j] -> A3[h][(i*32+j)][p] (bf16), coalesced via LDS.
// One block per (h,i): reads contiguous 8KB, writes contiguous rows.
// ---------------------------------------------------------------------------
__global__ __launch_bounds__(256)
void build_a3(const float* __restrict__ A, unsigned short* __restrict__ dst)
{
  __shared__ float ls[64 * 33];
  const int hi = blockIdx.x;            // h*32 + i
  const int h = hi >> 5, i = hi & 31;
  const int t = threadIdx.x;
  const float* srcb = A + (size_t)hi * 64 * 32;
  const int p = t >> 2, jq = (t & 3) * 8;
  const float4 v0 = *(const float4*)(srcb + p * 32 + jq);
  const float4 v1 = *(const float4*)(srcb + p * 32 + jq + 4);
  ls[p * 33 + jq + 0] = v0.x; ls[p * 33 + jq + 1] = v0.y;
  ls[p * 33 + jq + 2] = v0.z; ls[p * 33 + jq + 3] = v0.w;
  ls[p * 33 + jq + 4] = v1.x; ls[p * 33 + jq + 5] = v1.y;
  ls[p * 33 + jq + 6] = v1.z; ls[p * 33 + jq + 7] = v1.w;
  __syncthreads();
  const int j = t >> 3, p8 = (t & 7) * 8;
  unsigned short o[8];
#pragma unroll
  for (int q = 0; q < 8; ++q) o[q] = f2bf(ls[(p8 + q) * 33 + j]);
  *(s16x8*)(dst + (size_t)h * 65536 + (size_t)(i * 32 + j) * 64 + p8) = *(s16x8*)o;
}

// ---------------------------------------------------------------------------
// bf16 MFMA GEMM, C = A[M,K] * B  with B supplied transposed: BT[N,K].
// 128x128 tile, BK=32, 256 threads (4 waves, each 64x64), global_load_lds.
// EPI: 0 = bf16 out (+bias)                      (v = h@W_in+b_in)
//      1 = bf16 out to Mt chunk, (i,j)->(j,i) swizzled, blockIdx.z=head.
//      2 = f32 out = resid + acc + bias          (residual adds)
//      3 = bf16 out = gelu_exact(acc+bias)       (FFN mid)
// ---------------------------------------------------------------------------
#define BM 128
#define BN 128
#define BKK 32

template<int EPI>
__global__ __launch_bounds__(256)
void gemm_bt(const unsigned short* __restrict__ Abase, int lda,
             const unsigned short* __restrict__ BTbase, int ldb,
             const float* __restrict__ bias,
             const float* __restrict__ resid,
             void* __restrict__ Cout,
             int N, int K, int s0, int lsc)
{
  __shared__ __align__(16) unsigned short As[BM * BKK];
  __shared__ __align__(16) unsigned short Bs[BN * BKK];
  const int tid  = threadIdx.x;
  const int lane = tid & 63;
  const int m0 = blockIdx.x * BM;
  const int n0 = blockIdx.y * BN;
  const unsigned short* Ap  = Abase;
  const unsigned short* BTp = BTbase;
  if (EPI == 1) {
    const int h = blockIdx.z;
    Ap  += h * 64;                       // head column slice of v (lda=1024)
    BTp += (size_t)h * 1024 * 64;        // A3 per-head block
  }
  f32x4 acc[4][4] = {};
  const int wave = tid >> 6;
  const int wr = wave >> 1, wc = wave & 1;
  const int mrow = lane & 15;
  const int koff = (lane >> 4) * 8;
  const int SCm1 = (1 << lsc) - 1;

  for (int kk = 0; kk < K; kk += BKK) {
#pragma unroll
    for (int rep = 0; rep < 2; ++rep) {
      const int c = rep * 256 + tid;                  // chunk id 0..511
      const int rowp = m0 + (c >> 2);
      size_t grow;
      if (EPI == 1) grow = ((size_t)(rowp >> lsc) << 11) + (size_t)s0 + (rowp & SCm1);
      else          grow = (size_t)rowp;
      const unsigned short* ga = Ap + grow * lda + kk + (c & 3) * 8;
      unsigned short* la = &As[(size_t)(rep * 256 + (tid & 192)) * 8];
      __builtin_amdgcn_global_load_lds(
          (const __attribute__((address_space(1))) unsigned int*)ga,
          (__attribute__((address_space(3))) unsigned int*)la, 16, 0, 0);
      const unsigned short* gb = BTp + (size_t)(n0 + (c >> 2)) * ldb + kk + (c & 3) * 8;
      unsigned short* lb = &Bs[(size_t)(rep * 256 + (tid & 192)) * 8];
      __builtin_amdgcn_global_load_lds(
          (const __attribute__((address_space(1))) unsigned int*)gb,
          (__attribute__((address_space(3))) unsigned int*)lb, 16, 0, 0);
    }
    __syncthreads();
    bf16x8 af[4], bfr[4];
#pragma unroll
    for (int a = 0; a < 4; ++a)
      af[a] = *(const bf16x8*)&As[(wr * 64 + a * 16 + mrow) * BKK + koff];
#pragma unroll
    for (int b = 0; b < 4; ++b)
      bfr[b] = *(const bf16x8*)&Bs[(wc * 64 + b * 16 + mrow) * BKK + koff];
#pragma unroll
    for (int a = 0; a < 4; ++a)
#pragma unroll
      for (int b = 0; b < 4; ++b)
        acc[a][b] = __builtin_amdgcn_mfma_f32_16x16x32_bf16(af[a], bfr[b], acc[a][b], 0, 0, 0);
    __syncthreads();
  }

  const int crow = m0 + wr * 64 + (lane >> 4) * 4;
  const int ccol = n0 + wc * 64 + (lane & 15);
#pragma unroll
  for (int a = 0; a < 4; ++a) {
#pragma unroll
    for (int b = 0; b < 4; ++b) {
      const int col = ccol + b * 16;
#pragma unroll
      for (int q = 0; q < 4; ++q) {
        const int row = crow + a * 16 + q;
        const float val = acc[a][b][q];
        if (EPI == 0) {
          ((unsigned short*)Cout)[(size_t)row * N + col] = f2bf(val + bias[col]);
        } else if (EPI == 1) {
          const int bb = row >> lsc, sc = row & SCm1;  // local chunk coords
          const int h = blockIdx.z;
          const size_t off = ((((size_t)(bb * 16 + h)) << lsc) + sc) * 1024
                           + (size_t)(col & 31) * 32 + (col >> 5);   // [j][i]
          ((unsigned short*)Cout)[off] = f2bf(val);
        } else if (EPI == 2) {
          const size_t o = (size_t)row * N + col;
          ((float*)Cout)[o] = resid[o] + val + bias[col];
        } else {
          const float xv = val + bias[col];
          const float gl = 0.5f * xv * (1.0f + erff(xv * 0.70710678118654752f));
          ((unsigned short*)Cout)[(size_t)row * N + col] = f2bf(gl);
        }
      }
    }
  }
}

// ---------------------------------------------------------------------------
// MPS recurrence over one S-chunk.  One wave per (b,h); lane j (both halves)
// holds h[j].  Mt[bh][sc][j][i] (bf16): lane reads its contiguous 16 i's
// (32B), half sums i in [16*half,16*half+16), cross-half shfl_xor combines.
// Depth-16 register prefetch ring keeps ~32 loads (32KB/wave) in flight so
// per-step cost is max(compute ~200cy, HBM latency/16).  Branchless tail via
// clamped prefetch address keeps the outstanding-load count uniform.
// ---------------------------------------------------------------------------
#define SCAN_P 16

__global__ __launch_bounds__(64)
void mps_scan_chunk(const unsigned short* __restrict__ Mt,
                    unsigned short* __restrict__ hs,
                    float* __restrict__ hstate, int s0, int SC)
{
  const int bh = blockIdx.x;           // b*16 + h
  const int b = bh >> 4, h = bh & 15;
  const int lane = threadIdx.x;
  const int j = lane & 31, half = lane >> 5;
  const unsigned short* base = Mt + (size_t)bh * SC * 1024 + j * 32 + half * 16;
  unsigned short* hout = hs + ((size_t)b * 2048 + s0) * 512 + h * 32 + j;
  float hc = (s0 == 0) ? 0.17677669529663687f : hstate[bh * 32 + j];

  s16x8 ring[SCAN_P][2];
#pragma unroll
  for (int k = 0; k < SCAN_P; ++k) {
    const unsigned short* pb = base + (size_t)k * 1024;
    ring[k][0] = *(const s16x8*)(pb);
    ring[k][1] = *(const s16x8*)(pb + 8);
  }
  for (int st = 0; st < SC; st += SCAN_P) {
#pragma unroll
    for (int k = 0; k < SCAN_P; ++k) {
      const int s = st + k;
      const s16x8 c0 = ring[k][0];
      const s16x8 c1 = ring[k][1];
      // issue prefetch for step s+P (clamped: uniform load count, no branch)
      const int sp = (s + SCAN_P < SC) ? (s + SCAN_P) : (SC - 1);
      const unsigned short* pb = base + (size_t)sp * 1024;
      ring[k][0] = *(const s16x8*)(pb);
      ring[k][1] = *(const s16x8*)(pb + 8);
      // broadcast h values and tree-accumulate z_j partial for this half
      float p[8];
#pragma unroll
      for (int t = 0; t < 4; ++t) {
        const float h0 = __shfl(hc, half * 16 + 2 * t, 64);
        const float h1 = __shfl(hc, half * 16 + 2 * t + 1, 64);
        p[t] = fmaf(h1, bf2f((unsigned short)c0[2 * t + 1]),
                    h0 * bf2f((unsigned short)c0[2 * t]));
      }
#pragma unroll
      for (int t = 0; t < 4; ++t) {
        const float h0 = __shfl(hc, half * 16 + 8 + 2 * t, 64);
        const float h1 = __shfl(hc, half * 16 + 8 + 2 * t + 1, 64);
        p[4 + t] = fmaf(h1, bf2f((unsigned short)c1[2 * t + 1]),
                        h0 * bf2f((unsigned short)c1[2 * t]));
      }
      const float q0 = p[0] + p[1], q1 = p[2] + p[3];
      const float q2 = p[4] + p[5], q3 = p[6] + p[7];
      float tot = (q0 + q1) + (q2 + q3);
      tot += __shfl_xor(tot, 32, 64);
      const float e = __expf(2.0f * tot);
      hc = 1.0f - 2.0f / (e + 1.0f);   // tanh, saturates correctly
      if (half == 0) hout[(size_t)s * 512] = f2bf(hc);
    }
  }
  if (half == 0) hstate[bh * 32 + j] = hc;
}

// ---------------------------------------------------------------------------
extern "C" void kernel_launch(void* const* d_in, const int* in_sizes, int n_in,
                              void* d_out, int out_size, void* d_ws, size_t ws_size,
                              hipStream_t stream)
{
  const float* x     = (const float*)d_in[0];
  const float* ln1g  = (const float*)d_in[1];
  const float* ln1b  = (const float*)d_in[2];
  const float* W_in  = (const float*)d_in[3];
  const float* b_in  = (const float*)d_in[4];
  const float* Amps  = (const float*)d_in[5];
  const float* W_out = (const float*)d_in[6];
  const float* b_out = (const float*)d_in[7];
  const float* ln2g  = (const float*)d_in[8];
  const float* ln2b  = (const float*)d_in[9];
  const float* W1    = (const float*)d_in[10];
  const float* b1    = (const float*)d_in[11];
  const float* W2    = (const float*)d_in[12];
  const float* b2    = (const float*)d_in[13];
  float* out = (float*)d_out;          // also serves as x2 (branch-1 residual)

  char* w = (char*)d_ws;
  size_t off = 0;
  auto alloc = [&](size_t bytes) {
    char* p = w + off; off += (bytes + 255) & ~(size_t)255; return p;
  };
  unsigned short* W_inT  = (unsigned short*)alloc(2ull * 1024 * 1024);
  unsigned short* W_outT = (unsigned short*)alloc(2ull * 1024 * 512);
  unsigned short* W1T    = (unsigned short*)alloc(2ull * 4096 * 1024);
  unsigned short* W2T    = (unsigned short*)alloc(2ull * 1024 * 4096);
  unsigned short* A3     = (unsigned short*)alloc(2ull * 16 * 1024 * 64);
  unsigned short* hb     = (unsigned short*)alloc(2ull * 8192 * 1024);
  unsigned short* vb     = (unsigned short*)alloc(2ull * 8192 * 1024);
  float*          hstate = (float*)alloc(4ull * 64 * 32);
  const size_t fixed = off;

  // --- choose Mt S-chunk (SC) and FFN row-chunk (MC) to fit ws_size ---
  auto mt_bytes = [](int sc) { return (size_t)64 * sc * 1024 * 2; };
  auto f1_bytes = [](int mc) { return (size_t)mc * 4096 * 2; };
  const size_t avail = (ws_size > fixed + 256) ? (ws_size - fixed - 256) : 0;
  int SC = 2048, MC = 8192;
  for (;;) {
    const size_t ma = mt_bytes(SC), fa = f1_bytes(MC);
    const size_t region = ma > fa ? ma : fa;
    if (region <= avail) break;
    if (ma >= fa && SC > 128) SC >>= 1;
    else if (MC > 1024)       MC >>= 1;
    else if (SC > 128)        SC >>= 1;
    else break;
  }
  int lsc = 0; while ((1 << lsc) < SC) ++lsc;
  const size_t ma = mt_bytes(SC), fa = f1_bytes(MC);
  unsigned short* Mt = (unsigned short*)alloc(ma > fa ? ma : fa);
  unsigned short* f1 = Mt;              // temporally disjoint with Mt use
  unsigned short* hsb = hb;             // h dead after v-GEMM; hs dead before LN2
  unsigned short* h2b = hb;             // LN2 output overwrites hs (then dead)

  // weight prep (runs every call; small, coalesced)
  transpose_tile_bf16<<<dim3(32, 32),  256, 0, stream>>>(W_in,  W_inT,  1024, 1024);
  transpose_tile_bf16<<<dim3(32, 16),  256, 0, stream>>>(W_out, W_outT, 512,  1024);
  transpose_tile_bf16<<<dim3(128, 32), 256, 0, stream>>>(W1,    W1T,    1024, 4096);
  transpose_tile_bf16<<<dim3(32, 128), 256, 0, stream>>>(W2,    W2T,    4096, 1024);
  build_a3<<<512, 256, 0, stream>>>(Amps, A3);

  // branch 1: MPS recurrence
  ln_bf16_kernel<<<8192, 256, 0, stream>>>(x, ln1g, ln1b, hb);
  gemm_bt<0><<<dim3(64, 8, 1), 256, 0, stream>>>(hb, 1024, W_inT, 1024, b_in, nullptr, vb, 1024, 1024, 0, 0);
  for (int s0 = 0; s0 < 2048; s0 += SC) {
    gemm_bt<1><<<dim3(4 * SC / 128, 8, 16), 256, 0, stream>>>(vb, 1024, A3, 64, nullptr, nullptr, Mt, 1024, 64, s0, lsc);
    mps_scan_chunk<<<64, 64, 0, stream>>>(Mt, hsb, hstate, s0, SC);
  }
  gemm_bt<2><<<dim3(64, 8, 1), 256, 0, stream>>>(hsb, 512, W_outT, 512, b_out, x, out, 1024, 512, 0, 0);

  // branch 2: FFN (out holds x2; final GEMM adds residual in place)
  ln_bf16_kernel<<<8192, 256, 0, stream>>>(out, ln2g, ln2b, h2b);
  for (int r0 = 0; r0 < 8192; r0 += MC) {
    gemm_bt<3><<<dim3(MC / 128, 32, 1), 256, 0, stream>>>(h2b + (size_t)r0 * 1024, 1024, W1T, 1024, b1, nullptr, f1, 4096, 1024, 0, 0);
    gemm_bt<2><<<dim3(MC / 128, 8, 1), 256, 0, stream>>>(f1, 4096, W2T, 4096, b2, out + (size_t)r0 * 1024, out + (size_t)r0 * 1024, 1024, 4096, 0, 0);
  }

  (void)in_sizes; (void)n_in; (void)out_size; (void)ws_size;
}

// Round 5
// 1831.892 us; speedup vs baseline: 1.0359x; 1.0053x over previous
//
#include <hip/hip_runtime.h>
#include <stdint.h>
#include <math.h>

// ---------------------------------------------------------------------------
// HybridTransformerBlock: LN1 -> v=h@W_in+b -> per-head MPS scan -> +x
//                         LN2 -> GELU FFN -> +x2
// B=4 S=2048 D=1024 H=16 DH=32 DP=64 DFF=4096
// Workspace-adaptive: Mt (scan transfer matrices) and f1 (FFN mid) are
// chunked to fit whatever ws_size the harness provides.
// ---------------------------------------------------------------------------

typedef __attribute__((ext_vector_type(8))) __bf16 bf16x8;   // MFMA A/B operand
typedef __attribute__((ext_vector_type(8))) short  s16x8;    // raw 16B load
typedef __attribute__((ext_vector_type(4))) float  f32x4;    // MFMA C/D

__device__ __forceinline__ float bf2f(unsigned short u) {
  union { unsigned int i; float f; } c; c.i = ((unsigned int)u) << 16; return c.f;
}
__device__ __forceinline__ unsigned short f2bf(float f) {
  union { float f; unsigned int i; } c; c.f = f;
  unsigned int x = c.i;
  return (unsigned short)((x + 0x7FFFu + ((x >> 16) & 1u)) >> 16);
}

// ---------------------------------------------------------------------------
// LayerNorm (fp32 in) -> bf16 out.  One block per row of 1024.
// ---------------------------------------------------------------------------
__global__ __launch_bounds__(256)
void ln_bf16_kernel(const float* __restrict__ x, const float* __restrict__ g,
                    const float* __restrict__ b, unsigned short* __restrict__ out)
{
  const int row = blockIdx.x;
  const int t = threadIdx.x;
  const float4 v = ((const float4*)(x + (size_t)row * 1024))[t];
  float s  = v.x + v.y + v.z + v.w;
  float s2 = v.x*v.x + v.y*v.y + v.z*v.z + v.w*v.w;
#pragma unroll
  for (int o = 32; o > 0; o >>= 1) { s += __shfl_down(s, o, 64); s2 += __shfl_down(s2, o, 64); }
  __shared__ float ws1[4], ws2[4];
  if ((t & 63) == 0) { ws1[t >> 6] = s; ws2[t >> 6] = s2; }
  __syncthreads();
  const float ts  = ws1[0] + ws1[1] + ws1[2] + ws1[3];
  const float ts2 = ws2[0] + ws2[1] + ws2[2] + ws2[3];
  const float mean = ts * (1.0f / 1024.0f);
  const float var  = ts2 * (1.0f / 1024.0f) - mean * mean;
  const float inv  = rsqrtf(var + 1e-5f);
  const float4 gg = ((const float4*)g)[t];
  const float4 bb = ((const float4*)b)[t];
  ushort4 o4;
  o4.x = f2bf((v.x - mean) * inv * gg.x + bb.x);
  o4.y = f2bf((v.y - mean) * inv * gg.y + bb.y);
  o4.z = f2bf((v.z - mean) * inv * gg.z + bb.z);
  o4.w = f2bf((v.w - mean) * inv * gg.w + bb.w);
  ((ushort4*)(out + (size_t)row * 1024))[t] = o4;
}

// ---------------------------------------------------------------------------
// Coalesced LDS-tiled fp32 [R,C] -> bf16 [C,R] transpose.  32x32 tiles.
// Grid (C/32, R/32), block 256.
// ---------------------------------------------------------------------------
__global__ __launch_bounds__(256)
void transpose_tile_bf16(const float* __restrict__ src, unsigned short* __restrict__ dst,
                         int R, int C)
{
  __shared__ float ls[32 * 33];
  const int t = threadIdx.x;
  const int c0 = blockIdx.x * 32, r0 = blockIdx.y * 32;
  const int tr = t >> 3, tc = (t & 7) * 4;
  const float4 v = *(const float4*)(src + (size_t)(r0 + tr) * C + c0 + tc);
  ls[tr * 33 + tc + 0] = v.x;
  ls[tr * 33 + tc + 1] = v.y;
  ls[tr * 33 + tc + 2] = v.z;
  ls[tr * 33 + tc + 3] = v.w;
  __syncthreads();
  const int oc = t >> 3;           // source col handled by this thread
  const int orr = (t & 7) * 4;     // source row group
  ushort4 o;
  o.x = f2bf(ls[(orr + 0) * 33 + oc]);
  o.y = f2bf(ls[(orr + 1) * 33 + oc]);
  o.z = f2bf(ls[(orr + 2) * 33 + oc]);
  o.w = f2bf(ls[(orr + 3) * 33 + oc]);
  *(ushort4*)(dst + (size_t)(c0 + oc) * R + r0 + orr) = o;
}

// ---------------------------------------------------------------------------
// A[h,i,p,j] -> A3[h][(i*32+j)][p] (bf16), coalesced via LDS.
// One block per (h,i): reads contiguous 8KB, writes contiguous rows.
// ---------------------------------------------------------------------------
__global__ __launch_bounds__(256)
void build_a3(const float* __restrict__ A, unsigned short* __restrict__ dst)
{
  __shared__ float ls[64 * 33];
  const int hi = blockIdx.x;            // h*32 + i
  const int h = hi >> 5, i = hi & 31;
  const int t = threadIdx.x;
  const float* srcb = A + (size_t)hi * 64 * 32;
  const int p = t >> 2, jq = (t & 3) * 8;
  const float4 v0 = *(const float4*)(srcb + p * 32 + jq);
  const float4 v1 = *(const float4*)(srcb + p * 32 + jq + 4);
  ls[p * 33 + jq + 0] = v0.x; ls[p * 33 + jq + 1] = v0.y;
  ls[p * 33 + jq + 2] = v0.z; ls[p * 33 + jq + 3] = v0.w;
  ls[p * 33 + jq + 4] = v1.x; ls[p * 33 + jq + 5] = v1.y;
  ls[p * 33 + jq + 6] = v1.z; ls[p * 33 + jq + 7] = v1.w;
  __syncthreads();
  const int j = t >> 3, p8 = (t & 7) * 8;
  unsigned short o[8];
#pragma unroll
  for (int q = 0; q < 8; ++q) o[q] = f2bf(ls[(p8 + q) * 33 + j]);
  *(s16x8*)(dst + (size_t)h * 65536 + (size_t)(i * 32 + j) * 64 + p8) = *(s16x8*)o;
}

// ---------------------------------------------------------------------------
// bf16 MFMA GEMM, C = A[M,K] * B  with B supplied transposed: BT[N,K].
// 128x128 tile, BK=32, 256 threads (4 waves, each 64x64), global_load_lds.
// EPI: 0 = bf16 out (+bias)                      (v = h@W_in+b_in)
//      1 = bf16 out to Mt chunk, (i,j)->(j,i) swizzled, blockIdx.z=head.
//      2 = f32 out = resid + acc + bias          (residual adds)
//      3 = bf16 out = gelu_exact(acc+bias)       (FFN mid)
// ---------------------------------------------------------------------------
#define BM 128
#define BN 128
#define BKK 32

template<int EPI>
__global__ __launch_bounds__(256)
void gemm_bt(const unsigned short* __restrict__ Abase, int lda,
             const unsigned short* __restrict__ BTbase, int ldb,
             const float* __restrict__ bias,
             const float* __restrict__ resid,
             void* __restrict__ Cout,
             int N, int K, int s0, int lsc)
{
  __shared__ __align__(16) unsigned short As[BM * BKK];
  __shared__ __align__(16) unsigned short Bs[BN * BKK];
  const int tid  = threadIdx.x;
  const int lane = tid & 63;
  const int m0 = blockIdx.x * BM;
  const int n0 = blockIdx.y * BN;
  const unsigned short* Ap  = Abase;
  const unsigned short* BTp = BTbase;
  if (EPI == 1) {
    const int h = blockIdx.z;
    Ap  += h * 64;                       // head column slice of v (lda=1024)
    BTp += (size_t)h * 1024 * 64;        // A3 per-head block
  }
  f32x4 acc[4][4] = {};
  const int wave = tid >> 6;
  const int wr = wave >> 1, wc = wave & 1;
  const int mrow = lane & 15;
  const int koff = (lane >> 4) * 8;
  const int SCm1 = (1 << lsc) - 1;

  for (int kk = 0; kk < K; kk += BKK) {
#pragma unroll
    for (int rep = 0; rep < 2; ++rep) {
      const int c = rep * 256 + tid;                  // chunk id 0..511
      const int rowp = m0 + (c >> 2);
      size_t grow;
      if (EPI == 1) grow = ((size_t)(rowp >> lsc) << 11) + (size_t)s0 + (rowp & SCm1);
      else          grow = (size_t)rowp;
      const unsigned short* ga = Ap + grow * lda + kk + (c & 3) * 8;
      unsigned short* la = &As[(size_t)(rep * 256 + (tid & 192)) * 8];
      __builtin_amdgcn_global_load_lds(
          (const __attribute__((address_space(1))) unsigned int*)ga,
          (__attribute__((address_space(3))) unsigned int*)la, 16, 0, 0);
      const unsigned short* gb = BTp + (size_t)(n0 + (c >> 2)) * ldb + kk + (c & 3) * 8;
      unsigned short* lb = &Bs[(size_t)(rep * 256 + (tid & 192)) * 8];
      __builtin_amdgcn_global_load_lds(
          (const __attribute__((address_space(1))) unsigned int*)gb,
          (__attribute__((address_space(3))) unsigned int*)lb, 16, 0, 0);
    }
    __syncthreads();
    bf16x8 af[4], bfr[4];
#pragma unroll
    for (int a = 0; a < 4; ++a)
      af[a] = *(const bf16x8*)&As[(wr * 64 + a * 16 + mrow) * BKK + koff];
#pragma unroll
    for (int b = 0; b < 4; ++b)
      bfr[b] = *(const bf16x8*)&Bs[(wc * 64 + b * 16 + mrow) * BKK + koff];
#pragma unroll
    for (int a = 0; a < 4; ++a)
#pragma unroll
      for (int b = 0; b < 4; ++b)
        acc[a][b] = __builtin_amdgcn_mfma_f32_16x16x32_bf16(af[a], bfr[b], acc[a][b], 0, 0, 0);
    __syncthreads();
  }

  const int crow = m0 + wr * 64 + (lane >> 4) * 4;
  const int ccol = n0 + wc * 64 + (lane & 15);
#pragma unroll
  for (int a = 0; a < 4; ++a) {
#pragma unroll
    for (int b = 0; b < 4; ++b) {
      const int col = ccol + b * 16;
#pragma unroll
      for (int q = 0; q < 4; ++q) {
        const int row = crow + a * 16 + q;
        const float val = acc[a][b][q];
        if (EPI == 0) {
          ((unsigned short*)Cout)[(size_t)row * N + col] = f2bf(val + bias[col]);
        } else if (EPI == 1) {
          const int bb = row >> lsc, sc = row & SCm1;  // local chunk coords
          const int h = blockIdx.z;
          const size_t off = ((((size_t)(bb * 16 + h)) << lsc) + sc) * 1024
                           + (size_t)(col & 31) * 32 + (col >> 5);   // [j][i]
          ((unsigned short*)Cout)[off] = f2bf(val);
        } else if (EPI == 2) {
          const size_t o = (size_t)row * N + col;
          ((float*)Cout)[o] = resid[o] + val + bias[col];
        } else {
          const float xv = val + bias[col];
          const float gl = 0.5f * xv * (1.0f + erff(xv * 0.70710678118654752f));
          ((unsigned short*)Cout)[(size_t)row * N + col] = f2bf(gl);
        }
      }
    }
  }
}

// ---------------------------------------------------------------------------
// MPS recurrence over one S-chunk.  One wave per (b,h); lane j (both halves)
// holds h[j].  Mt[bh][sc][j][i] (bf16): lane reads its contiguous 16 i's
// (32B), half sums i in [16*half,16*half+16), cross-half shfl_xor combines.
// Depth-16 register prefetch ring (128 VGPRs) keeps 32 loads in flight.
// __launch_bounds__(64,1): 1 wave/SIMD -> up to 512 VGPRs, NO SPILL (R3's
// failure: default budget 84 VGPRs spilled the ring to scratch).
// ---------------------------------------------------------------------------
#define SCAN_P 16

__global__ __launch_bounds__(64, 1)
void mps_scan_chunk(const unsigned short* __restrict__ Mt,
                    unsigned short* __restrict__ hs,
                    float* __restrict__ hstate, int s0, int SC)
{
  const int bh = blockIdx.x;           // b*16 + h
  const int b = bh >> 4, h = bh & 15;
  const int lane = threadIdx.x;
  const int j = lane & 31, half = lane >> 5;
  const unsigned short* base = Mt + (size_t)bh * SC * 1024 + j * 32 + half * 16;
  unsigned short* hout = hs + ((size_t)b * 2048 + s0) * 512 + h * 32 + j;
  float hc = (s0 == 0) ? 0.17677669529663687f : hstate[bh * 32 + j];

  s16x8 ring[SCAN_P][2];
#pragma unroll
  for (int k = 0; k < SCAN_P; ++k) {
    const unsigned short* pb = base + (size_t)k * 1024;
    ring[k][0] = *(const s16x8*)(pb);
    ring[k][1] = *(const s16x8*)(pb + 8);
  }
  for (int st = 0; st < SC; st += SCAN_P) {
#pragma unroll
    for (int k = 0; k < SCAN_P; ++k) {
      const int s = st + k;
      const s16x8 c0 = ring[k][0];
      const s16x8 c1 = ring[k][1];
      // issue prefetch for step s+P (clamped: uniform load count, no branch)
      const int sp = (s + SCAN_P < SC) ? (s + SCAN_P) : (SC - 1);
      const unsigned short* pb = base + (size_t)sp * 1024;
      ring[k][0] = *(const s16x8*)(pb);
      ring[k][1] = *(const s16x8*)(pb + 8);
      // broadcast h values and tree-accumulate z_j partial for this half
      float p[8];
#pragma unroll
      for (int t = 0; t < 4; ++t) {
        const float h0 = __shfl(hc, half * 16 + 2 * t, 64);
        const float h1 = __shfl(hc, half * 16 + 2 * t + 1, 64);
        p[t] = fmaf(h1, bf2f((unsigned short)c0[2 * t + 1]),
                    h0 * bf2f((unsigned short)c0[2 * t]));
      }
#pragma unroll
      for (int t = 0; t < 4; ++t) {
        const float h0 = __shfl(hc, half * 16 + 8 + 2 * t, 64);
        const float h1 = __shfl(hc, half * 16 + 8 + 2 * t + 1, 64);
        p[4 + t] = fmaf(h1, bf2f((unsigned short)c1[2 * t + 1]),
                        h0 * bf2f((unsigned short)c1[2 * t]));
      }
      const float q0 = p[0] + p[1], q1 = p[2] + p[3];
      const float q2 = p[4] + p[5], q3 = p[6] + p[7];
      float tot = (q0 + q1) + (q2 + q3);
      tot += __shfl_xor(tot, 32, 64);
      const float e = __expf(2.0f * tot);
      hc = fmaf(-2.0f, __builtin_amdgcn_rcpf(e + 1.0f), 1.0f);  // tanh
      if (half == 0) hout[(size_t)s * 512] = f2bf(hc);
    }
  }
  if (half == 0) hstate[bh * 32 + j] = hc;
}

// ---------------------------------------------------------------------------
extern "C" void kernel_launch(void* const* d_in, const int* in_sizes, int n_in,
                              void* d_out, int out_size, void* d_ws, size_t ws_size,
                              hipStream_t stream)
{
  const float* x     = (const float*)d_in[0];
  const float* ln1g  = (const float*)d_in[1];
  const float* ln1b  = (const float*)d_in[2];
  const float* W_in  = (const float*)d_in[3];
  const float* b_in  = (const float*)d_in[4];
  const float* Amps  = (const float*)d_in[5];
  const float* W_out = (const float*)d_in[6];
  const float* b_out = (const float*)d_in[7];
  const float* ln2g  = (const float*)d_in[8];
  const float* ln2b  = (const float*)d_in[9];
  const float* W1    = (const float*)d_in[10];
  const float* b1    = (const float*)d_in[11];
  const float* W2    = (const float*)d_in[12];
  const float* b2    = (const float*)d_in[13];
  float* out = (float*)d_out;          // also serves as x2 (branch-1 residual)

  char* w = (char*)d_ws;
  size_t off = 0;
  auto alloc = [&](size_t bytes) {
    char* p = w + off; off += (bytes + 255) & ~(size_t)255; return p;
  };
  unsigned short* W_inT  = (unsigned short*)alloc(2ull * 1024 * 1024);
  unsigned short* W_outT = (unsigned short*)alloc(2ull * 1024 * 512);
  unsigned short* W1T    = (unsigned short*)alloc(2ull * 4096 * 1024);
  unsigned short* W2T    = (unsigned short*)alloc(2ull * 1024 * 4096);
  unsigned short* A3     = (unsigned short*)alloc(2ull * 16 * 1024 * 64);
  unsigned short* hb     = (unsigned short*)alloc(2ull * 8192 * 1024);
  unsigned short* vb     = (unsigned short*)alloc(2ull * 8192 * 1024);
  float*          hstate = (float*)alloc(4ull * 64 * 32);
  const size_t fixed = off;

  // --- choose Mt S-chunk (SC) and FFN row-chunk (MC) to fit ws_size ---
  auto mt_bytes = [](int sc) { return (size_t)64 * sc * 1024 * 2; };
  auto f1_bytes = [](int mc) { return (size_t)mc * 4096 * 2; };
  const size_t avail = (ws_size > fixed + 256) ? (ws_size - fixed - 256) : 0;
  int SC = 2048, MC = 8192;
  for (;;) {
    const size_t ma = mt_bytes(SC), fa = f1_bytes(MC);
    const size_t region = ma > fa ? ma : fa;
    if (region <= avail) break;
    if (ma >= fa && SC > 128) SC >>= 1;
    else if (MC > 1024)       MC >>= 1;
    else if (SC > 128)        SC >>= 1;
    else break;
  }
  int lsc = 0; while ((1 << lsc) < SC) ++lsc;
  const size_t ma = mt_bytes(SC), fa = f1_bytes(MC);
  unsigned short* Mt = (unsigned short*)alloc(ma > fa ? ma : fa);
  unsigned short* f1 = Mt;              // temporally disjoint with Mt use
  unsigned short* hsb = hb;             // h dead after v-GEMM; hs dead before LN2
  unsigned short* h2b = hb;             // LN2 output overwrites hs (then dead)

  // weight prep (runs every call; small, coalesced)
  transpose_tile_bf16<<<dim3(32, 32),  256, 0, stream>>>(W_in,  W_inT,  1024, 1024);
  transpose_tile_bf16<<<dim3(32, 16),  256, 0, stream>>>(W_out, W_outT, 512,  1024);
  transpose_tile_bf16<<<dim3(128, 32), 256, 0, stream>>>(W1,    W1T,    1024, 4096);
  transpose_tile_bf16<<<dim3(32, 128), 256, 0, stream>>>(W2,    W2T,    4096, 1024);
  build_a3<<<512, 256, 0, stream>>>(Amps, A3);

  // branch 1: MPS recurrence
  ln_bf16_kernel<<<8192, 256, 0, stream>>>(x, ln1g, ln1b, hb);
  gemm_bt<0><<<dim3(64, 8, 1), 256, 0, stream>>>(hb, 1024, W_inT, 1024, b_in, nullptr, vb, 1024, 1024, 0, 0);
  for (int s0 = 0; s0 < 2048; s0 += SC) {
    gemm_bt<1><<<dim3(4 * SC / 128, 8, 16), 256, 0, stream>>>(vb, 1024, A3, 64, nullptr, nullptr, Mt, 1024, 64, s0, lsc);
    mps_scan_chunk<<<64, 64, 0, stream>>>(Mt, hsb, hstate, s0, SC);
  }
  gemm_bt<2><<<dim3(64, 8, 1), 256, 0, stream>>>(hsb, 512, W_outT, 512, b_out, x, out, 1024, 512, 0, 0);

  // branch 2: FFN (out holds x2; final GEMM adds residual in place)
  ln_bf16_kernel<<<8192, 256, 0, stream>>>(out, ln2g, ln2b, h2b);
  for (int r0 = 0; r0 < 8192; r0 += MC) {
    gemm_bt<3><<<dim3(MC / 128, 32, 1), 256, 0, stream>>>(h2b + (size_t)r0 * 1024, 1024, W1T, 1024, b1, nullptr, f1, 4096, 1024, 0, 0);
    gemm_bt<2><<<dim3(MC / 128, 8, 1), 256, 0, stream>>>(f1, 4096, W2T, 4096, b2, out + (size_t)r0 * 1024, out + (size_t)r0 * 1024, 1024, 4096, 0, 0);
  }

  (void)in_sizes; (void)n_in; (void)out_size; (void)ws_size;
}

// Round 6
// 1633.735 us; speedup vs baseline: 1.1615x; 1.1213x over previous
//
#include <hip/hip_runtime.h>
#include <stdint.h>
#include <math.h>

// ---------------------------------------------------------------------------
// HybridTransformerBlock: LN1 -> v=h@W_in+b -> per-head MPS scan -> +x
//                         LN2 -> GELU FFN -> +x2
// B=4 S=2048 D=1024 H=16 DH=32 DP=64 DFF=4096
// Workspace-adaptive: Mt (scan transfer matrices) and f1 (FFN mid) are
// chunked to fit whatever ws_size the harness provides.
// ---------------------------------------------------------------------------

typedef __attribute__((ext_vector_type(8))) __bf16 bf16x8;   // MFMA A/B operand
typedef __attribute__((ext_vector_type(8))) short  s16x8;    // raw 16B load
typedef __attribute__((ext_vector_type(4))) float  f32x4;    // MFMA C/D

__device__ __forceinline__ float bf2f(unsigned short u) {
  union { unsigned int i; float f; } c; c.i = ((unsigned int)u) << 16; return c.f;
}
__device__ __forceinline__ unsigned short f2bf(float f) {
  union { float f; unsigned int i; } c; c.f = f;
  unsigned int x = c.i;
  return (unsigned short)((x + 0x7FFFu + ((x >> 16) & 1u)) >> 16);
}

// ---------------------------------------------------------------------------
// LayerNorm (fp32 in) -> bf16 out.  One block per row of 1024.
// ---------------------------------------------------------------------------
__global__ __launch_bounds__(256)
void ln_bf16_kernel(const float* __restrict__ x, const float* __restrict__ g,
                    const float* __restrict__ b, unsigned short* __restrict__ out)
{
  const int row = blockIdx.x;
  const int t = threadIdx.x;
  const float4 v = ((const float4*)(x + (size_t)row * 1024))[t];
  float s  = v.x + v.y + v.z + v.w;
  float s2 = v.x*v.x + v.y*v.y + v.z*v.z + v.w*v.w;
#pragma unroll
  for (int o = 32; o > 0; o >>= 1) { s += __shfl_down(s, o, 64); s2 += __shfl_down(s2, o, 64); }
  __shared__ float ws1[4], ws2[4];
  if ((t & 63) == 0) { ws1[t >> 6] = s; ws2[t >> 6] = s2; }
  __syncthreads();
  const float ts  = ws1[0] + ws1[1] + ws1[2] + ws1[3];
  const float ts2 = ws2[0] + ws2[1] + ws2[2] + ws2[3];
  const float mean = ts * (1.0f / 1024.0f);
  const float var  = ts2 * (1.0f / 1024.0f) - mean * mean;
  const float inv  = rsqrtf(var + 1e-5f);
  const float4 gg = ((const float4*)g)[t];
  const float4 bb = ((const float4*)b)[t];
  ushort4 o4;
  o4.x = f2bf((v.x - mean) * inv * gg.x + bb.x);
  o4.y = f2bf((v.y - mean) * inv * gg.y + bb.y);
  o4.z = f2bf((v.z - mean) * inv * gg.z + bb.z);
  o4.w = f2bf((v.w - mean) * inv * gg.w + bb.w);
  ((ushort4*)(out + (size_t)row * 1024))[t] = o4;
}

// ---------------------------------------------------------------------------
// Coalesced LDS-tiled fp32 [R,C] -> bf16 [C,R] transpose.  32x32 tiles.
// ---------------------------------------------------------------------------
__global__ __launch_bounds__(256)
void transpose_tile_bf16(const float* __restrict__ src, unsigned short* __restrict__ dst,
                         int R, int C)
{
  __shared__ float ls[32 * 33];
  const int t = threadIdx.x;
  const int c0 = blockIdx.x * 32, r0 = blockIdx.y * 32;
  const int tr = t >> 3, tc = (t & 7) * 4;
  const float4 v = *(const float4*)(src + (size_t)(r0 + tr) * C + c0 + tc);
  ls[tr * 33 + tc + 0] = v.x;
  ls[tr * 33 + tc + 1] = v.y;
  ls[tr * 33 + tc + 2] = v.z;
  ls[tr * 33 + tc + 3] = v.w;
  __syncthreads();
  const int oc = t >> 3;
  const int orr = (t & 7) * 4;
  ushort4 o;
  o.x = f2bf(ls[(orr + 0) * 33 + oc]);
  o.y = f2bf(ls[(orr + 1) * 33 + oc]);
  o.z = f2bf(ls[(orr + 2) * 33 + oc]);
  o.w = f2bf(ls[(orr + 3) * 33 + oc]);
  *(ushort4*)(dst + (size_t)(c0 + oc) * R + r0 + orr) = o;
}

// ---------------------------------------------------------------------------
// A[h,i,p,j] -> A3[h][(i*32+j)][p] (bf16), coalesced via LDS.
// ---------------------------------------------------------------------------
__global__ __launch_bounds__(256)
void build_a3(const float* __restrict__ A, unsigned short* __restrict__ dst)
{
  __shared__ float ls[64 * 33];
  const int hi = blockIdx.x;            // h*32 + i
  const int h = hi >> 5, i = hi & 31;
  const int t = threadIdx.x;
  const float* srcb = A + (size_t)hi * 64 * 32;
  const int p = t >> 2, jq = (t & 3) * 8;
  const float4 v0 = *(const float4*)(srcb + p * 32 + jq);
  const float4 v1 = *(const float4*)(srcb + p * 32 + jq + 4);
  ls[p * 33 + jq + 0] = v0.x; ls[p * 33 + jq + 1] = v0.y;
  ls[p * 33 + jq + 2] = v0.z; ls[p * 33 + jq + 3] = v0.w;
  ls[p * 33 + jq + 4] = v1.x; ls[p * 33 + jq + 5] = v1.y;
  ls[p * 33 + jq + 6] = v1.z; ls[p * 33 + jq + 7] = v1.w;
  __syncthreads();
  const int j = t >> 3, p8 = (t & 7) * 8;
  unsigned short o[8];
#pragma unroll
  for (int q = 0; q < 8; ++q) o[q] = f2bf(ls[(p8 + q) * 33 + j]);
  *(s16x8*)(dst + (size_t)h * 65536 + (size_t)(i * 32 + j) * 64 + p8) = *(s16x8*)o;
}

// ---------------------------------------------------------------------------
// bf16 MFMA GEMM, C = A[M,K] * B  with B supplied transposed: BT[N,K].
// 128x128 tile, BK=32, 256 threads (4 waves, each 64x64), global_load_lds.
// ---------------------------------------------------------------------------
#define BM 128
#define BN 128
#define BKK 32

template<int EPI>
__global__ __launch_bounds__(256)
void gemm_bt(const unsigned short* __restrict__ Abase, int lda,
             const unsigned short* __restrict__ BTbase, int ldb,
             const float* __restrict__ bias,
             const float* __restrict__ resid,
             void* __restrict__ Cout,
             int N, int K, int s0, int lsc)
{
  __shared__ __align__(16) unsigned short As[BM * BKK];
  __shared__ __align__(16) unsigned short Bs[BN * BKK];
  const int tid  = threadIdx.x;
  const int lane = tid & 63;
  const int m0 = blockIdx.x * BM;
  const int n0 = blockIdx.y * BN;
  const unsigned short* Ap  = Abase;
  const unsigned short* BTp = BTbase;
  if (EPI == 1) {
    const int h = blockIdx.z;
    Ap  += h * 64;
    BTp += (size_t)h * 1024 * 64;
  }
  f32x4 acc[4][4] = {};
  const int wave = tid >> 6;
  const int wr = wave >> 1, wc = wave & 1;
  const int mrow = lane & 15;
  const int koff = (lane >> 4) * 8;
  const int SCm1 = (1 << lsc) - 1;

  for (int kk = 0; kk < K; kk += BKK) {
#pragma unroll
    for (int rep = 0; rep < 2; ++rep) {
      const int c = rep * 256 + tid;
      const int rowp = m0 + (c >> 2);
      size_t grow;
      if (EPI == 1) grow = ((size_t)(rowp >> lsc) << 11) + (size_t)s0 + (rowp & SCm1);
      else          grow = (size_t)rowp;
      const unsigned short* ga = Ap + grow * lda + kk + (c & 3) * 8;
      unsigned short* la = &As[(size_t)(rep * 256 + (tid & 192)) * 8];
      __builtin_amdgcn_global_load_lds(
          (const __attribute__((address_space(1))) unsigned int*)ga,
          (__attribute__((address_space(3))) unsigned int*)la, 16, 0, 0);
      const unsigned short* gb = BTp + (size_t)(n0 + (c >> 2)) * ldb + kk + (c & 3) * 8;
      unsigned short* lb = &Bs[(size_t)(rep * 256 + (tid & 192)) * 8];
      __builtin_amdgcn_global_load_lds(
          (const __attribute__((address_space(1))) unsigned int*)gb,
          (__attribute__((address_space(3))) unsigned int*)lb, 16, 0, 0);
    }
    __syncthreads();
    bf16x8 af[4], bfr[4];
#pragma unroll
    for (int a = 0; a < 4; ++a)
      af[a] = *(const bf16x8*)&As[(wr * 64 + a * 16 + mrow) * BKK + koff];
#pragma unroll
    for (int b = 0; b < 4; ++b)
      bfr[b] = *(const bf16x8*)&Bs[(wc * 64 + b * 16 + mrow) * BKK + koff];
#pragma unroll
    for (int a = 0; a < 4; ++a)
#pragma unroll
      for (int b = 0; b < 4; ++b)
        acc[a][b] = __builtin_amdgcn_mfma_f32_16x16x32_bf16(af[a], bfr[b], acc[a][b], 0, 0, 0);
    __syncthreads();
  }

  const int crow = m0 + wr * 64 + (lane >> 4) * 4;
  const int ccol = n0 + wc * 64 + (lane & 15);
#pragma unroll
  for (int a = 0; a < 4; ++a) {
#pragma unroll
    for (int b = 0; b < 4; ++b) {
      const int col = ccol + b * 16;
#pragma unroll
      for (int q = 0; q < 4; ++q) {
        const int row = crow + a * 16 + q;
        const float val = acc[a][b][q];
        if (EPI == 0) {
          ((unsigned short*)Cout)[(size_t)row * N + col] = f2bf(val + bias[col]);
        } else if (EPI == 1) {
          const int bb = row >> lsc, sc = row & SCm1;
          const int h = blockIdx.z;
          const size_t off = ((((size_t)(bb * 16 + h)) << lsc) + sc) * 1024
                           + (size_t)(col & 31) * 32 + (col >> 5);   // [j][i]
          ((unsigned short*)Cout)[off] = f2bf(val);
        } else if (EPI == 2) {
          const size_t o = (size_t)row * N + col;
          ((float*)Cout)[o] = resid[o] + val + bias[col];
        } else {
          const float xv = val + bias[col];
          const float gl = 0.5f * xv * (1.0f + erff(xv * 0.70710678118654752f));
          ((unsigned short*)Cout)[(size_t)row * N + col] = f2bf(gl);
        }
      }
    }
  }
}

// ---------------------------------------------------------------------------
// MPS recurrence over one S-chunk.  One wave per (b,h); lane j (both halves)
// holds h[j].  Per step the wave consumes one 2KB row of Mt[bh] (layout
// [j][i]).
//
// R3/R5 lesson: a VGPR prefetch ring is silently de-pipelined (loads sunk to
// their uses; VGPR stayed 84).  Here prefetch uses global_load_lds into a
// 16-slot LDS ring (side-effecting intrinsic: cannot be sunk into a register
// use) with a manual counted `s_waitcnt vmcnt(30)` -- 15 slots (30 loads)
// stay in flight across steps, AITER-style.  The global source address is
// pre-swizzled per lane so LDS-linear order == consumption order: lane l
// fetches elements (l&31)*32+(l>>5)*16 (+8 for the second instr) into
// slot + l*16B, and ds_reads back at lane*16B -- conflict-free b128 reads.
// LDS->reg is double-buffered one step ahead.  Per-step order:
//   lgkmcnt(0)                      (prior ds_reads retired -> WAR-safe)
//   issue 2x global_load_lds slot s%16  (target step s+16, clamped)
//   vmcnt(30)                       (targets <= s+1 resident in LDS)
//   ds_read slot (s+1)%16 -> nxt
//   compute on cur; swap
// ---------------------------------------------------------------------------
#define SCAN_P 16

__global__ __launch_bounds__(64, 1)
void mps_scan_chunk(const unsigned short* __restrict__ Mt,
                    unsigned short* __restrict__ hs,
                    float* __restrict__ hstate, int s0, int SC)
{
  __shared__ __align__(16) unsigned short ring[SCAN_P * 1024];
  const int bh = blockIdx.x;           // b*16 + h
  const int b = bh >> 4, h = bh & 15;
  const int lane = threadIdx.x;
  const int j = lane & 31, half = lane >> 5;
  const unsigned short* rowbase = Mt + (size_t)bh * SC * 1024;
  const int src_off = j * 32 + half * 16;        // per-lane source swizzle
  unsigned short* hout = hs + ((size_t)b * 2048 + s0) * 512 + h * 32 + j;
  float hc = (s0 == 0) ? 0.17677669529663687f : hstate[bh * 32 + j];

  auto issue = [&](int t, int slot) {
    const unsigned short* g = rowbase + (size_t)t * 1024 + src_off;
    unsigned short* l = &ring[slot * 1024];
    __builtin_amdgcn_global_load_lds(
        (const __attribute__((address_space(1))) unsigned int*)g,
        (__attribute__((address_space(3))) unsigned int*)l, 16, 0, 0);
    __builtin_amdgcn_global_load_lds(
        (const __attribute__((address_space(1))) unsigned int*)(g + 8),
        (__attribute__((address_space(3))) unsigned int*)(l + 512), 16, 0, 0);
  };

  // prologue: fill all 16 slots (SC >= 128 > SCAN_P always)
#pragma unroll
  for (int k = 0; k < SCAN_P; ++k) issue(k, k);
  asm volatile("s_waitcnt vmcnt(30)" ::: "memory");   // slot 0 resident
  s16x8 curA = *(const s16x8*)&ring[lane * 8];
  s16x8 curB = *(const s16x8*)&ring[512 + lane * 8];

  for (int s = 0; s < SC; ++s) {
    // prior ds_reads (and bpermutes) retired -> safe to overwrite slot s%P
    asm volatile("s_waitcnt lgkmcnt(0)" ::: "memory");
    const int tp = (s + SCAN_P < SC) ? (s + SCAN_P) : (SC - 1);
    issue(tp, s & (SCAN_P - 1));
    asm volatile("s_waitcnt vmcnt(30)" ::: "memory"); // targets <= s+1 in LDS
    const int ns = (s + 1) & (SCAN_P - 1);
    s16x8 nxtA = *(const s16x8*)&ring[ns * 1024 + lane * 8];
    s16x8 nxtB = *(const s16x8*)&ring[ns * 1024 + 512 + lane * 8];

    // broadcast h values and tree-accumulate z_j partial for this half
    float p[8];
#pragma unroll
    for (int t = 0; t < 4; ++t) {
      const float h0 = __shfl(hc, half * 16 + 2 * t, 64);
      const float h1 = __shfl(hc, half * 16 + 2 * t + 1, 64);
      p[t] = fmaf(h1, bf2f((unsigned short)curA[2 * t + 1]),
                  h0 * bf2f((unsigned short)curA[2 * t]));
    }
#pragma unroll
    for (int t = 0; t < 4; ++t) {
      const float h0 = __shfl(hc, half * 16 + 8 + 2 * t, 64);
      const float h1 = __shfl(hc, half * 16 + 8 + 2 * t + 1, 64);
      p[4 + t] = fmaf(h1, bf2f((unsigned short)curB[2 * t + 1]),
                      h0 * bf2f((unsigned short)curB[2 * t]));
    }
    const float q0 = p[0] + p[1], q1 = p[2] + p[3];
    const float q2 = p[4] + p[5], q3 = p[6] + p[7];
    float tot = (q0 + q1) + (q2 + q3);
    tot += __shfl_xor(tot, 32, 64);
    const float e = __expf(2.0f * tot);
    hc = fmaf(-2.0f, __builtin_amdgcn_rcpf(e + 1.0f), 1.0f);  // tanh
    if (half == 0) hout[(size_t)s * 512] = f2bf(hc);
    curA = nxtA; curB = nxtB;
  }
  if (half == 0) hstate[bh * 32 + j] = hc;
}

// ---------------------------------------------------------------------------
extern "C" void kernel_launch(void* const* d_in, const int* in_sizes, int n_in,
                              void* d_out, int out_size, void* d_ws, size_t ws_size,
                              hipStream_t stream)
{
  const float* x     = (const float*)d_in[0];
  const float* ln1g  = (const float*)d_in[1];
  const float* ln1b  = (const float*)d_in[2];
  const float* W_in  = (const float*)d_in[3];
  const float* b_in  = (const float*)d_in[4];
  const float* Amps  = (const float*)d_in[5];
  const float* W_out = (const float*)d_in[6];
  const float* b_out = (const float*)d_in[7];
  const float* ln2g  = (const float*)d_in[8];
  const float* ln2b  = (const float*)d_in[9];
  const float* W1    = (const float*)d_in[10];
  const float* b1    = (const float*)d_in[11];
  const float* W2    = (const float*)d_in[12];
  const float* b2    = (const float*)d_in[13];
  float* out = (float*)d_out;          // also serves as x2 (branch-1 residual)

  char* w = (char*)d_ws;
  size_t off = 0;
  auto alloc = [&](size_t bytes) {
    char* p = w + off; off += (bytes + 255) & ~(size_t)255; return p;
  };
  unsigned short* W_inT  = (unsigned short*)alloc(2ull * 1024 * 1024);
  unsigned short* W_outT = (unsigned short*)alloc(2ull * 1024 * 512);
  unsigned short* W1T    = (unsigned short*)alloc(2ull * 4096 * 1024);
  unsigned short* W2T    = (unsigned short*)alloc(2ull * 1024 * 4096);
  unsigned short* A3     = (unsigned short*)alloc(2ull * 16 * 1024 * 64);
  unsigned short* hb     = (unsigned short*)alloc(2ull * 8192 * 1024);
  unsigned short* vb     = (unsigned short*)alloc(2ull * 8192 * 1024);
  float*          hstate = (float*)alloc(4ull * 64 * 32);
  const size_t fixed = off;

  // --- choose Mt S-chunk (SC) and FFN row-chunk (MC) to fit ws_size ---
  auto mt_bytes = [](int sc) { return (size_t)64 * sc * 1024 * 2; };
  auto f1_bytes = [](int mc) { return (size_t)mc * 4096 * 2; };
  const size_t avail = (ws_size > fixed + 256) ? (ws_size - fixed - 256) : 0;
  int SC = 2048, MC = 8192;
  for (;;) {
    const size_t ma = mt_bytes(SC), fa = f1_bytes(MC);
    const size_t region = ma > fa ? ma : fa;
    if (region <= avail) break;
    if (ma >= fa && SC > 128) SC >>= 1;
    else if (MC > 1024)       MC >>= 1;
    else if (SC > 128)        SC >>= 1;
    else break;
  }
  int lsc = 0; while ((1 << lsc) < SC) ++lsc;
  const size_t ma = mt_bytes(SC), fa = f1_bytes(MC);
  unsigned short* Mt = (unsigned short*)alloc(ma > fa ? ma : fa);
  unsigned short* f1 = Mt;              // temporally disjoint with Mt use
  unsigned short* hsb = hb;             // h dead after v-GEMM; hs dead before LN2
  unsigned short* h2b = hb;             // LN2 output overwrites hs (then dead)

  // weight prep (runs every call; small, coalesced)
  transpose_tile_bf16<<<dim3(32, 32),  256, 0, stream>>>(W_in,  W_inT,  1024, 1024);
  transpose_tile_bf16<<<dim3(32, 16),  256, 0, stream>>>(W_out, W_outT, 512,  1024);
  transpose_tile_bf16<<<dim3(128, 32), 256, 0, stream>>>(W1,    W1T,    1024, 4096);
  transpose_tile_bf16<<<dim3(32, 128), 256, 0, stream>>>(W2,    W2T,    4096, 1024);
  build_a3<<<512, 256, 0, stream>>>(Amps, A3);

  // branch 1: MPS recurrence
  ln_bf16_kernel<<<8192, 256, 0, stream>>>(x, ln1g, ln1b, hb);
  gemm_bt<0><<<dim3(64, 8, 1), 256, 0, stream>>>(hb, 1024, W_inT, 1024, b_in, nullptr, vb, 1024, 1024, 0, 0);
  for (int s0 = 0; s0 < 2048; s0 += SC) {
    gemm_bt<1><<<dim3(4 * SC / 128, 8, 16), 256, 0, stream>>>(vb, 1024, A3, 64, nullptr, nullptr, Mt, 1024, 64, s0, lsc);
    mps_scan_chunk<<<64, 64, 0, stream>>>(Mt, hsb, hstate, s0, SC);
  }
  gemm_bt<2><<<dim3(64, 8, 1), 256, 0, stream>>>(hsb, 512, W_outT, 512, b_out, x, out, 1024, 512, 0, 0);

  // branch 2: FFN (out holds x2; final GEMM adds residual in place)
  ln_bf16_kernel<<<8192, 256, 0, stream>>>(out, ln2g, ln2b, h2b);
  for (int r0 = 0; r0 < 8192; r0 += MC) {
    gemm_bt<3><<<dim3(MC / 128, 32, 1), 256, 0, stream>>>(h2b + (size_t)r0 * 1024, 1024, W1T, 1024, b1, nullptr, f1, 4096, 1024, 0, 0);
    gemm_bt<2><<<dim3(MC / 128, 8, 1), 256, 0, stream>>>(f1, 4096, W2T, 4096, b2, out + (size_t)r0 * 1024, out + (size_t)r0 * 1024, 1024, 4096, 0, 0);
  }

  (void)in_sizes; (void)n_in; (void)out_size; (void)ws_size;
}

// Round 7
// 1034.157 us; speedup vs baseline: 1.8349x; 1.5798x over previous
//
#include <hip/hip_runtime.h>
#include <stdint.h>
#include <math.h>

// ---------------------------------------------------------------------------
// HybridTransformerBlock: LN1 -> v=h@W_in+b -> per-head MPS scan -> +x
//                         LN2 -> GELU FFN -> +x2
// B=4 S=2048 D=1024 H=16 DH=32 DP=64 DFF=4096
// Workspace-adaptive: Mt (scan transfer matrices) and f1 (FFN mid) are
// chunked to fit whatever ws_size the harness provides.
// R7: A3 rows ordered (j*32+i) so the Mt GEMM's natural row-major output IS
// the scan's [j][i] layout -- epilogue scatter (131MB amplified writes,
// 4x335us) becomes plain coalesced rows.
// ---------------------------------------------------------------------------

typedef __attribute__((ext_vector_type(8))) __bf16 bf16x8;   // MFMA A/B operand
typedef __attribute__((ext_vector_type(8))) short  s16x8;    // raw 16B load
typedef __attribute__((ext_vector_type(4))) float  f32x4;    // MFMA C/D

__device__ __forceinline__ float bf2f(unsigned short u) {
  union { unsigned int i; float f; } c; c.i = ((unsigned int)u) << 16; return c.f;
}
__device__ __forceinline__ unsigned short f2bf(float f) {
  union { float f; unsigned int i; } c; c.f = f;
  unsigned int x = c.i;
  return (unsigned short)((x + 0x7FFFu + ((x >> 16) & 1u)) >> 16);
}

// ---------------------------------------------------------------------------
// LayerNorm (fp32 in) -> bf16 out.  One block per row of 1024.
// ---------------------------------------------------------------------------
__global__ __launch_bounds__(256)
void ln_bf16_kernel(const float* __restrict__ x, const float* __restrict__ g,
                    const float* __restrict__ b, unsigned short* __restrict__ out)
{
  const int row = blockIdx.x;
  const int t = threadIdx.x;
  const float4 v = ((const float4*)(x + (size_t)row * 1024))[t];
  float s  = v.x + v.y + v.z + v.w;
  float s2 = v.x*v.x + v.y*v.y + v.z*v.z + v.w*v.w;
#pragma unroll
  for (int o = 32; o > 0; o >>= 1) { s += __shfl_down(s, o, 64); s2 += __shfl_down(s2, o, 64); }
  __shared__ float ws1[4], ws2[4];
  if ((t & 63) == 0) { ws1[t >> 6] = s; ws2[t >> 6] = s2; }
  __syncthreads();
  const float ts  = ws1[0] + ws1[1] + ws1[2] + ws1[3];
  const float ts2 = ws2[0] + ws2[1] + ws2[2] + ws2[3];
  const float mean = ts * (1.0f / 1024.0f);
  const float var  = ts2 * (1.0f / 1024.0f) - mean * mean;
  const float inv  = rsqrtf(var + 1e-5f);
  const float4 gg = ((const float4*)g)[t];
  const float4 bb = ((const float4*)b)[t];
  ushort4 o4;
  o4.x = f2bf((v.x - mean) * inv * gg.x + bb.x);
  o4.y = f2bf((v.y - mean) * inv * gg.y + bb.y);
  o4.z = f2bf((v.z - mean) * inv * gg.z + bb.z);
  o4.w = f2bf((v.w - mean) * inv * gg.w + bb.w);
  ((ushort4*)(out + (size_t)row * 1024))[t] = o4;
}

// ---------------------------------------------------------------------------
// Coalesced LDS-tiled fp32 [R,C] -> bf16 [C,R] transpose.  32x32 tiles.
// ---------------------------------------------------------------------------
__global__ __launch_bounds__(256)
void transpose_tile_bf16(const float* __restrict__ src, unsigned short* __restrict__ dst,
                         int R, int C)
{
  __shared__ float ls[32 * 33];
  const int t = threadIdx.x;
  const int c0 = blockIdx.x * 32, r0 = blockIdx.y * 32;
  const int tr = t >> 3, tc = (t & 7) * 4;
  const float4 v = *(const float4*)(src + (size_t)(r0 + tr) * C + c0 + tc);
  ls[tr * 33 + tc + 0] = v.x;
  ls[tr * 33 + tc + 1] = v.y;
  ls[tr * 33 + tc + 2] = v.z;
  ls[tr * 33 + tc + 3] = v.w;
  __syncthreads();
  const int oc = t >> 3;
  const int orr = (t & 7) * 4;
  ushort4 o;
  o.x = f2bf(ls[(orr + 0) * 33 + oc]);
  o.y = f2bf(ls[(orr + 1) * 33 + oc]);
  o.z = f2bf(ls[(orr + 2) * 33 + oc]);
  o.w = f2bf(ls[(orr + 3) * 33 + oc]);
  *(ushort4*)(dst + (size_t)(c0 + oc) * R + r0 + orr) = o;
}

// ---------------------------------------------------------------------------
// A[h,i,p,j] -> A3[h][(j*32+i)][p] (bf16), coalesced via LDS.
// Row order (j*32+i) makes the Mt GEMM output land directly in the scan's
// [j][i] layout (no epilogue scatter).
// ---------------------------------------------------------------------------
__global__ __launch_bounds__(256)
void build_a3(const float* __restrict__ A, unsigned short* __restrict__ dst)
{
  __shared__ float ls[64 * 33];
  const int hi = blockIdx.x;            // h*32 + i
  const int h = hi >> 5, i = hi & 31;
  const int t = threadIdx.x;
  const float* srcb = A + (size_t)hi * 64 * 32;
  const int p = t >> 2, jq = (t & 3) * 8;
  const float4 v0 = *(const float4*)(srcb + p * 32 + jq);
  const float4 v1 = *(const float4*)(srcb + p * 32 + jq + 4);
  ls[p * 33 + jq + 0] = v0.x; ls[p * 33 + jq + 1] = v0.y;
  ls[p * 33 + jq + 2] = v0.z; ls[p * 33 + jq + 3] = v0.w;
  ls[p * 33 + jq + 4] = v1.x; ls[p * 33 + jq + 5] = v1.y;
  ls[p * 33 + jq + 6] = v1.z; ls[p * 33 + jq + 7] = v1.w;
  __syncthreads();
  const int j = t >> 3, p8 = (t & 7) * 8;
  unsigned short o[8];
#pragma unroll
  for (int q = 0; q < 8; ++q) o[q] = f2bf(ls[(p8 + q) * 33 + j]);
  *(s16x8*)(dst + (size_t)h * 65536 + (size_t)(j * 32 + i) * 64 + p8) = *(s16x8*)o;
}

// ---------------------------------------------------------------------------
// bf16 MFMA GEMM, C = A[M,K] * B  with B supplied transposed: BT[N,K].
// 128x128 tile, BK=32, 256 threads (4 waves, each 64x64), global_load_lds.
// EPI: 0 = bf16 out (+bias)            1 = bf16 out to Mt chunk (coalesced)
//      2 = f32 out = resid+acc+bias    3 = bf16 out = gelu(acc+bias)
// ---------------------------------------------------------------------------
#define BM 128
#define BN 128
#define BKK 32

template<int EPI>
__global__ __launch_bounds__(256)
void gemm_bt(const unsigned short* __restrict__ Abase, int lda,
             const unsigned short* __restrict__ BTbase, int ldb,
             const float* __restrict__ bias,
             const float* __restrict__ resid,
             void* __restrict__ Cout,
             int N, int K, int s0, int lsc)
{
  __shared__ __align__(16) unsigned short As[BM * BKK];
  __shared__ __align__(16) unsigned short Bs[BN * BKK];
  const int tid  = threadIdx.x;
  const int lane = tid & 63;
  const int m0 = blockIdx.x * BM;
  const int n0 = blockIdx.y * BN;
  const unsigned short* Ap  = Abase;
  const unsigned short* BTp = BTbase;
  if (EPI == 1) {
    const int h = blockIdx.z;
    Ap  += h * 64;
    BTp += (size_t)h * 1024 * 64;
  }
  f32x4 acc[4][4] = {};
  const int wave = tid >> 6;
  const int wr = wave >> 1, wc = wave & 1;
  const int mrow = lane & 15;
  const int koff = (lane >> 4) * 8;
  const int SCm1 = (1 << lsc) - 1;

  for (int kk = 0; kk < K; kk += BKK) {
#pragma unroll
    for (int rep = 0; rep < 2; ++rep) {
      const int c = rep * 256 + tid;
      const int rowp = m0 + (c >> 2);
      size_t grow;
      if (EPI == 1) grow = ((size_t)(rowp >> lsc) << 11) + (size_t)s0 + (rowp & SCm1);
      else          grow = (size_t)rowp;
      const unsigned short* ga = Ap + grow * lda + kk + (c & 3) * 8;
      unsigned short* la = &As[(size_t)(rep * 256 + (tid & 192)) * 8];
      __builtin_amdgcn_global_load_lds(
          (const __attribute__((address_space(1))) unsigned int*)ga,
          (__attribute__((address_space(3))) unsigned int*)la, 16, 0, 0);
      const unsigned short* gb = BTp + (size_t)(n0 + (c >> 2)) * ldb + kk + (c & 3) * 8;
      unsigned short* lb = &Bs[(size_t)(rep * 256 + (tid & 192)) * 8];
      __builtin_amdgcn_global_load_lds(
          (const __attribute__((address_space(1))) unsigned int*)gb,
          (__attribute__((address_space(3))) unsigned int*)lb, 16, 0, 0);
    }
    __syncthreads();
    bf16x8 af[4], bfr[4];
#pragma unroll
    for (int a = 0; a < 4; ++a)
      af[a] = *(const bf16x8*)&As[(wr * 64 + a * 16 + mrow) * BKK + koff];
#pragma unroll
    for (int b = 0; b < 4; ++b)
      bfr[b] = *(const bf16x8*)&Bs[(wc * 64 + b * 16 + mrow) * BKK + koff];
#pragma unroll
    for (int a = 0; a < 4; ++a)
#pragma unroll
      for (int b = 0; b < 4; ++b)
        acc[a][b] = __builtin_amdgcn_mfma_f32_16x16x32_bf16(af[a], bfr[b], acc[a][b], 0, 0, 0);
    __syncthreads();
  }

  const int crow = m0 + wr * 64 + (lane >> 4) * 4;
  const int ccol = n0 + wc * 64 + (lane & 15);
#pragma unroll
  for (int a = 0; a < 4; ++a) {
#pragma unroll
    for (int b = 0; b < 4; ++b) {
      const int col = ccol + b * 16;
#pragma unroll
      for (int q = 0; q < 4; ++q) {
        const int row = crow + a * 16 + q;
        const float val = acc[a][b][q];
        if (EPI == 0) {
          ((unsigned short*)Cout)[(size_t)row * N + col] = f2bf(val + bias[col]);
        } else if (EPI == 1) {
          const int bb = row >> lsc, sc = row & SCm1;   // local chunk coords
          const size_t off = ((((size_t)(bb * 16 + blockIdx.z)) << lsc) + sc) * 1024 + col;
          ((unsigned short*)Cout)[off] = f2bf(val);     // coalesced row write
        } else if (EPI == 2) {
          const size_t o = (size_t)row * N + col;
          ((float*)Cout)[o] = resid[o] + val + bias[col];
        } else {
          const float xv = val + bias[col];
          const float gl = 0.5f * xv * (1.0f + erff(xv * 0.70710678118654752f));
          ((unsigned short*)Cout)[(size_t)row * N + col] = f2bf(gl);
        }
      }
    }
  }
}

// ---------------------------------------------------------------------------
// MPS recurrence over one S-chunk.  One wave per (b,h); lane j (both halves)
// holds h[j].  16-slot LDS ring fed by global_load_lds with counted
// s_waitcnt vmcnt(30) (30 loads in flight) -- see R6 notes.  Mt row layout
// [j][i]: lane l fetches source elements (l&31)*32+(l>>5)*16 (+8 second
// chunk) into slot+l*16B; ds_read_b128 back at lane*16B, conflict-free.
// ---------------------------------------------------------------------------
#define SCAN_P 16

__global__ __launch_bounds__(64, 1)
void mps_scan_chunk(const unsigned short* __restrict__ Mt,
                    unsigned short* __restrict__ hs,
                    float* __restrict__ hstate, int s0, int SC)
{
  __shared__ __align__(16) unsigned short ring[SCAN_P * 1024];
  const int bh = blockIdx.x;           // b*16 + h
  const int b = bh >> 4, h = bh & 15;
  const int lane = threadIdx.x;
  const int j = lane & 31, half = lane >> 5;
  const unsigned short* rowbase = Mt + (size_t)bh * SC * 1024;
  const int src_off = j * 32 + half * 16;        // per-lane source swizzle
  unsigned short* hout = hs + ((size_t)b * 2048 + s0) * 512 + h * 32 + j;
  float hc = (s0 == 0) ? 0.17677669529663687f : hstate[bh * 32 + j];

  auto issue = [&](int t, int slot) {
    const unsigned short* g = rowbase + (size_t)t * 1024 + src_off;
    unsigned short* l = &ring[slot * 1024];
    __builtin_amdgcn_global_load_lds(
        (const __attribute__((address_space(1))) unsigned int*)g,
        (__attribute__((address_space(3))) unsigned int*)l, 16, 0, 0);
    __builtin_amdgcn_global_load_lds(
        (const __attribute__((address_space(1))) unsigned int*)(g + 8),
        (__attribute__((address_space(3))) unsigned int*)(l + 512), 16, 0, 0);
  };

  // prologue: fill all 16 slots (SC >= 128 > SCAN_P always)
#pragma unroll
  for (int k = 0; k < SCAN_P; ++k) issue(k, k);
  asm volatile("s_waitcnt vmcnt(30)" ::: "memory");   // slot 0 resident
  s16x8 curA = *(const s16x8*)&ring[lane * 8];
  s16x8 curB = *(const s16x8*)&ring[512 + lane * 8];

  for (int s = 0; s < SC; ++s) {
    // prior ds_reads retired -> safe to overwrite slot s%P
    asm volatile("s_waitcnt lgkmcnt(0)" ::: "memory");
    const int tp = (s + SCAN_P < SC) ? (s + SCAN_P) : (SC - 1);
    issue(tp, s & (SCAN_P - 1));
    asm volatile("s_waitcnt vmcnt(30)" ::: "memory"); // targets <= s+1 in LDS
    const int ns = (s + 1) & (SCAN_P - 1);
    s16x8 nxtA = *(const s16x8*)&ring[ns * 1024 + lane * 8];
    s16x8 nxtB = *(const s16x8*)&ring[ns * 1024 + 512 + lane * 8];

    // broadcast h values and tree-accumulate z_j partial for this half
    float p[8];
#pragma unroll
    for (int t = 0; t < 4; ++t) {
      const float h0 = __shfl(hc, half * 16 + 2 * t, 64);
      const float h1 = __shfl(hc, half * 16 + 2 * t + 1, 64);
      p[t] = fmaf(h1, bf2f((unsigned short)curA[2 * t + 1]),
                  h0 * bf2f((unsigned short)curA[2 * t]));
    }
#pragma unroll
    for (int t = 0; t < 4; ++t) {
      const float h0 = __shfl(hc, half * 16 + 8 + 2 * t, 64);
      const float h1 = __shfl(hc, half * 16 + 8 + 2 * t + 1, 64);
      p[4 + t] = fmaf(h1, bf2f((unsigned short)curB[2 * t + 1]),
                      h0 * bf2f((unsigned short)curB[2 * t]));
    }
    const float q0 = p[0] + p[1], q1 = p[2] + p[3];
    const float q2 = p[4] + p[5], q3 = p[6] + p[7];
    float tot = (q0 + q1) + (q2 + q3);
    tot += __shfl_xor(tot, 32, 64);
    const float e = __expf(2.0f * tot);
    hc = fmaf(-2.0f, __builtin_amdgcn_rcpf(e + 1.0f), 1.0f);  // tanh
    if (half == 0) hout[(size_t)s * 512] = f2bf(hc);
    curA = nxtA; curB = nxtB;
  }
  if (half == 0) hstate[bh * 32 + j] = hc;
}

// ---------------------------------------------------------------------------
extern "C" void kernel_launch(void* const* d_in, const int* in_sizes, int n_in,
                              void* d_out, int out_size, void* d_ws, size_t ws_size,
                              hipStream_t stream)
{
  const float* x     = (const float*)d_in[0];
  const float* ln1g  = (const float*)d_in[1];
  const float* ln1b  = (const float*)d_in[2];
  const float* W_in  = (const float*)d_in[3];
  const float* b_in  = (const float*)d_in[4];
  const float* Amps  = (const float*)d_in[5];
  const float* W_out = (const float*)d_in[6];
  const float* b_out = (const float*)d_in[7];
  const float* ln2g  = (const float*)d_in[8];
  const float* ln2b  = (const float*)d_in[9];
  const float* W1    = (const float*)d_in[10];
  const float* b1    = (const float*)d_in[11];
  const float* W2    = (const float*)d_in[12];
  const float* b2    = (const float*)d_in[13];
  float* out = (float*)d_out;          // also serves as x2 (branch-1 residual)

  char* w = (char*)d_ws;
  size_t off = 0;
  auto alloc = [&](size_t bytes) {
    char* p = w + off; off += (bytes + 255) & ~(size_t)255; return p;
  };
  unsigned short* W_inT  = (unsigned short*)alloc(2ull * 1024 * 1024);
  unsigned short* W_outT = (unsigned short*)alloc(2ull * 1024 * 512);
  unsigned short* W1T    = (unsigned short*)alloc(2ull * 4096 * 1024);
  unsigned short* W2T    = (unsigned short*)alloc(2ull * 1024 * 4096);
  unsigned short* A3     = (unsigned short*)alloc(2ull * 16 * 1024 * 64);
  unsigned short* hb     = (unsigned short*)alloc(2ull * 8192 * 1024);
  unsigned short* vb     = (unsigned short*)alloc(2ull * 8192 * 1024);
  float*          hstate = (float*)alloc(4ull * 64 * 32);
  const size_t fixed = off;

  // --- choose Mt S-chunk (SC) and FFN row-chunk (MC) to fit ws_size ---
  auto mt_bytes = [](int sc) { return (size_t)64 * sc * 1024 * 2; };
  auto f1_bytes = [](int mc) { return (size_t)mc * 4096 * 2; };
  const size_t avail = (ws_size > fixed + 256) ? (ws_size - fixed - 256) : 0;
  int SC = 2048, MC = 8192;
  for (;;) {
    const size_t ma = mt_bytes(SC), fa = f1_bytes(MC);
    const size_t region = ma > fa ? ma : fa;
    if (region <= avail) break;
    if (ma >= fa && SC > 128) SC >>= 1;
    else if (MC > 1024)       MC >>= 1;
    else if (SC > 128)        SC >>= 1;
    else break;
  }
  int lsc = 0; while ((1 << lsc) < SC) ++lsc;
  const size_t ma = mt_bytes(SC), fa = f1_bytes(MC);
  unsigned short* Mt = (unsigned short*)alloc(ma > fa ? ma : fa);
  unsigned short* f1 = Mt;              // temporally disjoint with Mt use
  unsigned short* hsb = hb;             // h dead after v-GEMM; hs dead before LN2
  unsigned short* h2b = hb;             // LN2 output overwrites hs (then dead)

  // weight prep (runs every call; small, coalesced)
  transpose_tile_bf16<<<dim3(32, 32),  256, 0, stream>>>(W_in,  W_inT,  1024, 1024);
  transpose_tile_bf16<<<dim3(32, 16),  256, 0, stream>>>(W_out, W_outT, 512,  1024);
  transpose_tile_bf16<<<dim3(128, 32), 256, 0, stream>>>(W1,    W1T,    1024, 4096);
  transpose_tile_bf16<<<dim3(32, 128), 256, 0, stream>>>(W2,    W2T,    4096, 1024);
  build_a3<<<512, 256, 0, stream>>>(Amps, A3);

  // branch 1: MPS recurrence
  ln_bf16_kernel<<<8192, 256, 0, stream>>>(x, ln1g, ln1b, hb);
  gemm_bt<0><<<dim3(64, 8, 1), 256, 0, stream>>>(hb, 1024, W_inT, 1024, b_in, nullptr, vb, 1024, 1024, 0, 0);
  for (int s0 = 0; s0 < 2048; s0 += SC) {
    gemm_bt<1><<<dim3(4 * SC / 128, 8, 16), 256, 0, stream>>>(vb, 1024, A3, 64, nullptr, nullptr, Mt, 1024, 64, s0, lsc);
    mps_scan_chunk<<<64, 64, 0, stream>>>(Mt, hsb, hstate, s0, SC);
  }
  gemm_bt<2><<<dim3(64, 8, 1), 256, 0, stream>>>(hsb, 512, W_outT, 512, b_out, x, out, 1024, 512, 0, 0);

  // branch 2: FFN (out holds x2; final GEMM adds residual in place)
  ln_bf16_kernel<<<8192, 256, 0, stream>>>(out, ln2g, ln2b, h2b);
  for (int r0 = 0; r0 < 8192; r0 += MC) {
    gemm_bt<3><<<dim3(MC / 128, 32, 1), 256, 0, stream>>>(h2b + (size_t)r0 * 1024, 1024, W1T, 1024, b1, nullptr, f1, 4096, 1024, 0, 0);
    gemm_bt<2><<<dim3(MC / 128, 8, 1), 256, 0, stream>>>(f1, 4096, W2T, 4096, b2, out + (size_t)r0 * 1024, out + (size_t)r0 * 1024, 1024, 4096, 0, 0);
  }

  (void)in_sizes; (void)n_in; (void)out_size; (void)ws_size;
}